// Round 10
// baseline (276.034 us; speedup 1.0000x reference)
//
#include <hip/hip_runtime.h>
#include <stdint.h>

// Problem constants
#define T_TOK   16384      // B*S
#define H_DIM   1024
#define IE_DIM  512
#define E_NUM   8
#define V_MAX   100000

typedef __attribute__((ext_vector_type(8))) short bf16x8;
typedef __attribute__((ext_vector_type(4))) float f32x4;
typedef unsigned long long ull;

__device__ __forceinline__ unsigned short f2bf(float f) {
  union { float f; unsigned u; } v; v.f = f;
  unsigned r = v.u + 0x7fffu + ((v.u >> 16) & 1u);
  return (unsigned short)(r >> 16);
}

__device__ __forceinline__ void gload16(const void* g, void* l) {
  __builtin_amdgcn_global_load_lds(
      (const __attribute__((address_space(1))) unsigned int*)g,
      (__attribute__((address_space(3))) unsigned int*)(unsigned int)(uintptr_t)l,
      16, 0, 0);
}

__device__ __forceinline__ int frag0(const bf16x8& v) {
  return ((const int*)&v)[0];
}

// ---------------- fused pre-pass: route (blocks 0..1023) + weight transpose (1024..4095) ----------------
__global__ __launch_bounds__(256) void k_pre(
    const float* __restrict__ mu, const int* __restrict__ tok,
    const float* __restrict__ mrw, int* __restrict__ eid,
    int* __restrict__ blockCnt,
    const float* __restrict__ wg, const float* __restrict__ wu,
    const float* __restrict__ wd, unsigned short* __restrict__ WgT,
    unsigned short* __restrict__ WuT, unsigned short* __restrict__ WdT) {
  __shared__ unsigned short lds[64][72];
  int tid = threadIdx.x;

  if (blockIdx.x < 1024) {
    int* cnt = (int*)&lds[0][0];
    if (tid < 8) cnt[tid] = 0;
    int wv = blockIdx.x * 4 + (tid >> 6);
    int t0 = wv * 4;
    int lane = tid & 63;
    const float4* mrw4 = (const float4*)mrw;

    float acc[4][E_NUM];
#pragma unroll
    for (int i = 0; i < 4; i++)
#pragma unroll
      for (int e = 0; e < E_NUM; e++) acc[i][e] = 0.f;

#pragma unroll
    for (int j = 0; j < 4; j++) {
      int idx = lane + 64 * j;
      float4 wr[E_NUM];
#pragma unroll
      for (int e = 0; e < E_NUM; e++) wr[e] = mrw4[e * 256 + idx];
#pragma unroll
      for (int i = 0; i < 4; i++) {
        float4 m = ((const float4*)(mu + (size_t)(t0 + i) * H_DIM))[idx];
#pragma unroll
        for (int e = 0; e < E_NUM; e++)
          acc[i][e] += m.x * wr[e].x + m.y * wr[e].y + m.z * wr[e].z + m.w * wr[e].w;
      }
    }
#pragma unroll
    for (int i = 0; i < 4; i++)
#pragma unroll
      for (int e = 0; e < E_NUM; e++)
#pragma unroll
        for (int off = 32; off >= 1; off >>= 1)
          acc[i][e] += __shfl_xor(acc[i][e], off, 64);

    __syncthreads();
#pragma unroll
    for (int i = 0; i < 4; i++) {
      int tv = tok[t0 + i];
      if (tv < 0) tv = 0;
      if (tv > V_MAX - 1) tv = V_MAX - 1;
      int base = tv & 7;
      int best = 0; float bs = -1e30f;
#pragma unroll
      for (int e = 0; e < E_NUM; e++) {
        float s = acc[i][e] + (e == base ? 10.f : 0.f);
        if (s > bs) { bs = s; best = e; }
      }
      if (lane == i) {
        eid[t0 + i] = best;
        atomicAdd(&cnt[best], 1);
      }
    }
    __syncthreads();
    if (tid < 8) blockCnt[blockIdx.x * 8 + tid] = cnt[tid];
  } else {
    int sel = (blockIdx.x - 1024) >> 10;
    int blk = blockIdx.x & 1023;
    const float* src; unsigned short* dst; int R, C;
    if (sel == 0)      { src = wg; dst = WgT; R = H_DIM; C = IE_DIM; }
    else if (sel == 1) { src = wu; dst = WuT; R = H_DIM; C = IE_DIM; }
    else               { src = wd; dst = WdT; R = IE_DIM; C = H_DIM; }
    int tpe = (R >> 6) * (C >> 6);
    int e = blk / tpe;
    int rem = blk % tpe;
    int tr = rem / (C >> 6);
    int tc = rem % (C >> 6);
    const float* s = src + (size_t)e * R * C;
    unsigned short* d = dst + (size_t)e * R * C;
    int r0 = tid >> 4;
    int c0 = (tid & 15) * 4;
#pragma unroll
    for (int i = 0; i < 4; i++) {
      int r = r0 + i * 16;
      float4 v = *(const float4*)(s + (size_t)(tr * 64 + r) * C + tc * 64 + c0);
      lds[r][c0 + 0] = f2bf(v.x); lds[r][c0 + 1] = f2bf(v.y);
      lds[r][c0 + 2] = f2bf(v.z); lds[r][c0 + 3] = f2bf(v.w);
    }
    __syncthreads();
    int oc = tid >> 2;
    int ob = (tid & 3) * 16;
    unsigned short tmp[16];
#pragma unroll
    for (int i = 0; i < 16; i++) tmp[i] = lds[ob + i][oc];
    uint4* dp = (uint4*)(d + (size_t)(tc * 64 + oc) * R + tr * 64 + ob);
    dp[0] = ((uint4*)tmp)[0];
    dp[1] = ((uint4*)tmp)[1];
  }
}

// ---------------- scan: packed 8x16-bit Hillis-Steele over 1024 blocks ----------------
__global__ __launch_bounds__(1024) void k_scan2(
    const int* __restrict__ blockCnt, int* __restrict__ blockBase,
    int* __restrict__ offsets, int* __restrict__ tileOff) {
  int b = threadIdx.x;
  __shared__ ull s0[1024], s1[1024];
  __shared__ int offL[8];
  const int4* p = (const int4*)(blockCnt + b * 8);
  int4 x0 = p[0], x1 = p[1];
  int c[8] = {x0.x, x0.y, x0.z, x0.w, x1.x, x1.y, x1.z, x1.w};
  ull v0 = (ull)c[0] | ((ull)c[1] << 16) | ((ull)c[2] << 32) | ((ull)c[3] << 48);
  ull v1 = (ull)c[4] | ((ull)c[5] << 16) | ((ull)c[6] << 32) | ((ull)c[7] << 48);
  s0[b] = v0; s1[b] = v1;
  __syncthreads();
  for (int st = 1; st < 1024; st <<= 1) {
    ull a0 = 0, a1 = 0;
    if (b >= st) { a0 = s0[b - st]; a1 = s1[b - st]; }
    __syncthreads();
    v0 += a0; v1 += a1;
    s0[b] = v0; s1[b] = v1;
    __syncthreads();
  }
  if (b == 1023) {
    int tot[8];
#pragma unroll
    for (int e = 0; e < 4; e++) tot[e] = (int)((v0 >> (16 * e)) & 0xFFFF);
#pragma unroll
    for (int e = 0; e < 4; e++) tot[4 + e] = (int)((v1 >> (16 * e)) & 0xFFFF);
    int s = 0, ts = 0;
    for (int e = 0; e < E_NUM; e++) {
      offsets[e] = s; offL[e] = s; tileOff[e] = ts;
      s += tot[e];
      ts += (tot[e] + 127) >> 7;
    }
    offsets[E_NUM] = s; tileOff[E_NUM] = ts;
  }
  __syncthreads();
  int be[8];
#pragma unroll
  for (int e = 0; e < 4; e++)
    be[e] = offL[e] + (int)((v0 >> (16 * e)) & 0xFFFF) - c[e];
#pragma unroll
  for (int e = 0; e < 4; e++)
    be[4 + e] = offL[4 + e] + (int)((v1 >> (16 * e)) & 0xFFFF) - c[4 + e];
  int4* q = (int4*)(blockBase + b * 8);
  q[0] = make_int4(be[0], be[1], be[2], be[3]);
  q[1] = make_int4(be[4], be[5], be[6], be[7]);
}

// ---------------- gather: deterministic rank, no atomics ----------------
__global__ __launch_bounds__(256) void k_gather(
    const float* __restrict__ hs, const int* __restrict__ eid,
    const int* __restrict__ blockBase, int* __restrict__ tokofrow,
    unsigned short* __restrict__ Xs) {
  int b = blockIdx.x;
  int tid = threadIdx.x;
  __shared__ int eL[16];
  __shared__ int posL[16];
  if (tid < 16) eL[tid] = eid[b * 16 + tid];
  __syncthreads();
  if (tid < 16) {
    int e = eL[tid];
    int r = 0;
    for (int j = 0; j < tid; j++) r += (eL[j] == e);
    int pos = blockBase[b * 8 + e] + r;
    posL[tid] = pos;
    tokofrow[pos] = b * 16 + tid;
  }
  __syncthreads();
  int w = tid >> 6, lane = tid & 63;
#pragma unroll
  for (int i = 0; i < 4; i++) {
    int li = w * 4 + i;
    int t = b * 16 + li;
    int pos = posL[li];
    const float4* src = (const float4*)(hs + (size_t)t * H_DIM);
    unsigned short* drow = Xs + (size_t)pos * H_DIM;
#pragma unroll
    for (int j = 0; j < 4; j++) {
      float4 v = src[lane + 64 * j];
      ushort4 bb;
      bb.x = f2bf(v.x); bb.y = f2bf(v.y); bb.z = f2bf(v.z); bb.w = f2bf(v.w);
      *(ushort4*)(drow + (lane + 64 * j) * 4) = bb;
    }
  }
}

// ---------------- GEMM1 (template ablation): h = silu(X Wg) * (X Wu) ----------------
// V=0 full; V=1 no-MFMA; V=2 no-ds_read; V=3 no-stage. R7 structure:
// BM=128,BN=128,BK=32, 8 waves 64x32 dual-acc, 3-buf depth-2 counted vmcnt.
template <int V>
__global__ __launch_bounds__(512) void k_gemm1_t(
    const unsigned short* __restrict__ Xs,
    const unsigned short* __restrict__ WgT,
    const unsigned short* __restrict__ WuT,
    unsigned short* __restrict__ Hb,
    const int* __restrict__ offsets, const int* __restrict__ tileOff) {
  // bijective XCD swizzle for nwg=540: q=67, r=4
  int bid0 = blockIdx.x;
  int xcd = bid0 & 7, seq = bid0 >> 3;
  int wg = (xcd < 4 ? xcd * 68 : 272 + (xcd - 4) * 67) + seq;
  int nt = wg & 3;
  int mlin = wg >> 2;
  if (mlin >= tileOff[E_NUM]) return;
  int e = 0;
#pragma unroll
  for (int i = 1; i < E_NUM; i++)
    if (mlin >= tileOff[i]) e = i;
  int mtile = mlin - tileOff[e];
  int segStart = offsets[e], segEnd = offsets[e + 1];
  int M = segEnd - segStart;

  __shared__ unsigned short Alds[3][128 * 32];
  __shared__ unsigned short Bglds[3][128 * 32];
  __shared__ unsigned short Bulds[3][128 * 32];

  int tid = threadIdx.x;
  int lane = tid & 63;
  int w = tid >> 6;
  int wm = w >> 2;
  int wn = w & 3;

  f32x4 accg[4][2], accu[4][2];
#pragma unroll
  for (int i = 0; i < 4; i++)
#pragma unroll
    for (int j = 0; j < 2; j++) {
      accg[i][j] = (f32x4)(0.f);
      accu[i][j] = (f32x4)(0.f);
    }

  int sr = tid >> 2;
  int sc = tid & 3;
  int scc = sc ^ ((sr >> 1) & 3);
  int grow = mtile * 128 + sr;
  if (grow > M - 1) grow = M - 1;
  const unsigned short* Arow = Xs + (size_t)(segStart + grow) * H_DIM + scc * 8;
  const unsigned short* Bgrow =
      WgT + (size_t)e * IE_DIM * H_DIM + (size_t)(nt * 128 + sr) * H_DIM + scc * 8;
  const unsigned short* Burow =
      WuT + (size_t)e * IE_DIM * H_DIM + (size_t)(nt * 128 + sr) * H_DIM + scc * 8;

#define STAGE1(buf, k0)                                            \
  {                                                                \
    gload16(Arow + (k0), (char*)Alds[buf] + tid * 16);             \
    gload16(Bgrow + (k0), (char*)Bglds[buf] + tid * 16);           \
    gload16(Burow + (k0), (char*)Bulds[buf] + tid * 16);           \
  }

  int kc = lane >> 4;
  int arow[4], browv[2];
#pragma unroll
  for (int mf = 0; mf < 4; mf++) arow[mf] = wm * 64 + mf * 16 + (lane & 15);
#pragma unroll
  for (int nf = 0; nf < 2; nf++) browv[nf] = wn * 32 + nf * 16 + (lane & 15);

  // constant frags for V2
  bf16x8 ca, cb;
#pragma unroll
  for (int i = 0; i < 8; i++) { ca[i] = (short)(lane + i); cb[i] = (short)(lane - i); }

  const int NT = H_DIM / 32;
  if (V != 3) { STAGE1(0, 0); STAGE1(1, 32); }

  int sink = 0;
  int cur = 0;
  for (int t = 0; t < NT; t++) {
    asm volatile("s_waitcnt vmcnt(3)" ::: "memory");
    __builtin_amdgcn_s_barrier();
    __builtin_amdgcn_sched_barrier(0);
    int tn = t + 2; if (tn >= NT) tn -= NT;
    int nbuf = cur + 2; if (nbuf >= 3) nbuf -= 3;
    if (V != 3) STAGE1(nbuf, tn * 32);

    bf16x8 a[4], bg[2], bu[2];
    if (V != 2) {
#pragma unroll
      for (int mf = 0; mf < 4; mf++) {
        int row = arow[mf];
        int byte = row * 64 + ((kc ^ ((row >> 1) & 3)) << 4);
        a[mf] = *(const bf16x8*)((const char*)Alds[cur] + byte);
      }
#pragma unroll
      for (int nf = 0; nf < 2; nf++) {
        int row = browv[nf];
        int byte = row * 64 + ((kc ^ ((row >> 1) & 3)) << 4);
        bg[nf] = *(const bf16x8*)((const char*)Bglds[cur] + byte);
        bu[nf] = *(const bf16x8*)((const char*)Bulds[cur] + byte);
      }
    } else {
#pragma unroll
      for (int mf = 0; mf < 4; mf++) a[mf] = ca;
#pragma unroll
      for (int nf = 0; nf < 2; nf++) { bg[nf] = cb; bu[nf] = cb; }
    }

    if (V != 1) {
      __builtin_amdgcn_s_setprio(1);
#pragma unroll
      for (int mf = 0; mf < 4; mf++)
#pragma unroll
        for (int nf = 0; nf < 2; nf++) {
          accg[mf][nf] = __builtin_amdgcn_mfma_f32_16x16x32_bf16(
              a[mf], bg[nf], accg[mf][nf], 0, 0, 0);
          accu[mf][nf] = __builtin_amdgcn_mfma_f32_16x16x32_bf16(
              a[mf], bu[nf], accu[mf][nf], 0, 0, 0);
        }
      __builtin_amdgcn_s_setprio(0);
    } else {
      // keep ds_reads live with cheap xor folds
#pragma unroll
      for (int mf = 0; mf < 4; mf++) sink ^= frag0(a[mf]);
#pragma unroll
      for (int nf = 0; nf < 2; nf++) { sink ^= frag0(bg[nf]); sink ^= frag0(bu[nf]); }
    }
    cur = (cur + 1 == 3) ? 0 : cur + 1;
  }
#undef STAGE1
  asm volatile("s_waitcnt vmcnt(0)" ::: "memory");

  if (V == 1) {
    // opaque-dead use: segStart is loaded from memory, never this large
    if (segStart > 0x7ffffff0) ((int*)Hb)[0] = sink;
  }

  int rowBase = segStart + mtile * 128 + wm * 64;
#pragma unroll
  for (int mf = 0; mf < 4; mf++)
#pragma unroll
    for (int nf = 0; nf < 2; nf++) {
      int col = nt * 128 + wn * 32 + nf * 16 + (lane & 15);
#pragma unroll
      for (int j = 0; j < 4; j++) {
        int r = rowBase + mf * 16 + (lane >> 4) * 4 + j;
        if (r < segEnd) {
          float g = accg[mf][nf][j];
          float u = accu[mf][nf][j];
          float h = (g / (1.f + __expf(-g))) * u;
          Hb[(size_t)r * IE_DIM + col] = f2bf(h);
        }
      }
    }
}

// ---------------- GEMM2: out[tok] = h Wd, fp32 scatter (R7 config) ----------------
__global__ __launch_bounds__(512) void k_gemm2(
    const unsigned short* __restrict__ Hb,
    const unsigned short* __restrict__ WdT,
    float* __restrict__ out,
    const int* __restrict__ offsets, const int* __restrict__ tileOff,
    const int* __restrict__ tokofrow) {
  // bijective XCD swizzle for nwg=1080: q=135, r=0
  int bid0 = blockIdx.x;
  int wg = (bid0 & 7) * 135 + (bid0 >> 3);
  int nt = wg & 7;
  int mlin = wg >> 3;
  if (mlin >= tileOff[E_NUM]) return;
  int e = 0;
#pragma unroll
  for (int i = 1; i < E_NUM; i++)
    if (mlin >= tileOff[i]) e = i;
  int mtile = mlin - tileOff[e];
  int segStart = offsets[e], segEnd = offsets[e + 1];
  int M = segEnd - segStart;

  __shared__ unsigned short Alds[3][128 * 32];
  __shared__ unsigned short Blds[3][128 * 32];

  int tid = threadIdx.x;
  int lane = tid & 63;
  int w = tid >> 6;
  int wm = w >> 2;
  int wn = w & 3;

  f32x4 acc[4][2];
#pragma unroll
  for (int i = 0; i < 4; i++)
#pragma unroll
    for (int j = 0; j < 2; j++) acc[i][j] = (f32x4)(0.f);

  int sr = tid >> 2;
  int sc = tid & 3;
  int scc = sc ^ ((sr >> 1) & 3);
  int grow = mtile * 128 + sr;
  if (grow > M - 1) grow = M - 1;
  const unsigned short* Arow = Hb + (size_t)(segStart + grow) * IE_DIM + scc * 8;
  const unsigned short* Brow =
      WdT + (size_t)e * H_DIM * IE_DIM + (size_t)(nt * 128 + sr) * IE_DIM + scc * 8;

#define STAGE2(buf, k0)                                            \
  {                                                                \
    gload16(Arow + (k0), (char*)Alds[buf] + tid * 16);             \
    gload16(Brow + (k0), (char*)Blds[buf] + tid * 16);             \
  }

  int kc = lane >> 4;
  int arow[4], browv[2];
#pragma unroll
  for (int mf = 0; mf < 4; mf++) arow[mf] = wm * 64 + mf * 16 + (lane & 15);
#pragma unroll
  for (int nf = 0; nf < 2; nf++) browv[nf] = wn * 32 + nf * 16 + (lane & 15);

  const int NT = IE_DIM / 32;
  STAGE2(0, 0);
  STAGE2(1, 32);

  int cur = 0;
  for (int t = 0; t < NT; t++) {
    asm volatile("s_waitcnt vmcnt(2)" ::: "memory");
    __builtin_amdgcn_s_barrier();
    __builtin_amdgcn_sched_barrier(0);
    int tn = t + 2; if (tn >= NT) tn -= NT;
    int nbuf = cur + 2; if (nbuf >= 3) nbuf -= 3;
    STAGE2(nbuf, tn * 32);

    bf16x8 a[4], b[2];
#pragma unroll
    for (int mf = 0; mf < 4; mf++) {
      int row = arow[mf];
      int byte = row * 64 + ((kc ^ ((row >> 1) & 3)) << 4);
      a[mf] = *(const bf16x8*)((const char*)Alds[cur] + byte);
    }
#pragma unroll
    for (int nf = 0; nf < 2; nf++) {
      int row = browv[nf];
      int byte = row * 64 + ((kc ^ ((row >> 1) & 3)) << 4);
      b[nf] = *(const bf16x8*)((const char*)Blds[cur] + byte);
    }
    __builtin_amdgcn_s_setprio(1);
#pragma unroll
    for (int mf = 0; mf < 4; mf++)
#pragma unroll
      for (int nf = 0; nf < 2; nf++)
        acc[mf][nf] = __builtin_amdgcn_mfma_f32_16x16x32_bf16(
            a[mf], b[nf], acc[mf][nf], 0, 0, 0);
    __builtin_amdgcn_s_setprio(0);
    cur = (cur + 1 == 3) ? 0 : cur + 1;
  }
#undef STAGE2
  asm volatile("s_waitcnt vmcnt(0)" ::: "memory");

  int rowBase = segStart + mtile * 128 + wm * 64;
#pragma unroll
  for (int mf = 0; mf < 4; mf++)
#pragma unroll
    for (int nf = 0; nf < 2; nf++) {
      int col = nt * 128 + wn * 32 + nf * 16 + (lane & 15);
#pragma unroll
      for (int j = 0; j < 4; j++) {
        int r = rowBase + mf * 16 + (lane >> 4) * 4 + j;
        if (r < segEnd) {
          int t = tokofrow[r];
          out[(size_t)t * H_DIM + col] = acc[mf][nf][j];
        }
      }
    }
}

// ---------------- workspace layout (bytes) ----------------
#define WS_XS    ((size_t)0)             // 32MB
#define WS_WGT   ((size_t)33554432)      // 8MB
#define WS_WUT   ((size_t)41943040)      // 8MB
#define WS_WDT   ((size_t)50331648)      // 8MB
#define WS_HB    ((size_t)58720256)      // 16MB
#define WS_EID   ((size_t)75497472)      // 64KB
#define WS_TOK   ((size_t)75563008)      // 64KB
#define WS_OFF   ((size_t)75628544)      // offsets/tileOff (1KB)
#define WS_BC    ((size_t)75629568)      // blockCnt 32KB
#define WS_BB    ((size_t)75662336)      // blockBase 32KB

extern "C" void kernel_launch(void* const* d_in, const int* in_sizes, int n_in,
                              void* d_out, int out_size, void* d_ws, size_t ws_size,
                              hipStream_t stream) {
  const float* hs  = (const float*)d_in[0];
  const int*   tok = (const int*)d_in[1];
  const float* mu  = (const float*)d_in[2];
  const float* wg  = (const float*)d_in[3];
  const float* wu  = (const float*)d_in[4];
  const float* wd  = (const float*)d_in[5];
  const float* mrw = (const float*)d_in[6];
  float* out = (float*)d_out;
  char* ws = (char*)d_ws;

  unsigned short* Xs  = (unsigned short*)(ws + WS_XS);
  unsigned short* WgT = (unsigned short*)(ws + WS_WGT);
  unsigned short* WuT = (unsigned short*)(ws + WS_WUT);
  unsigned short* WdT = (unsigned short*)(ws + WS_WDT);
  unsigned short* Hb  = (unsigned short*)(ws + WS_HB);
  int* eid      = (int*)(ws + WS_EID);
  int* tokofrow = (int*)(ws + WS_TOK);
  int* offsets  = (int*)(ws + WS_OFF);   // [9]
  int* tileOff  = offsets + 16;          // [9]
  int* blockCnt = (int*)(ws + WS_BC);    // [1024][8]
  int* blockBase= (int*)(ws + WS_BB);    // [1024][8]

  k_pre<<<4096, 256, 0, stream>>>(mu, tok, mrw, eid, blockCnt,
                                  wg, wu, wd, WgT, WuT, WdT);
  k_scan2<<<1, 1024, 0, stream>>>(blockCnt, blockBase, offsets, tileOff);
  k_gather<<<1024, 256, 0, stream>>>(hs, eid, blockBase, tokofrow, Xs);
  // ---- ablation dispatches (results overwritten by the real V0 run) ----
  k_gemm1_t<1><<<135 * 4, 512, 0, stream>>>(Xs, WgT, WuT, Hb, offsets, tileOff);
  k_gemm1_t<2><<<135 * 4, 512, 0, stream>>>(Xs, WgT, WuT, Hb, offsets, tileOff);
  k_gemm1_t<3><<<135 * 4, 512, 0, stream>>>(Xs, WgT, WuT, Hb, offsets, tileOff);
  // ---- real run ----
  k_gemm1_t<0><<<135 * 4, 512, 0, stream>>>(Xs, WgT, WuT, Hb, offsets, tileOff);
  k_gemm2<<<135 * 8, 512, 0, stream>>>(Hb, WdT, out, offsets, tileOff, tokofrow);
}

// Round 11
// 189.176 us; speedup vs baseline: 1.4591x; 1.4591x over previous
//
#include <hip/hip_runtime.h>
#include <stdint.h>

// Problem constants
#define T_TOK   16384      // B*S
#define H_DIM   1024
#define IE_DIM  512
#define E_NUM   8
#define V_MAX   100000

typedef __attribute__((ext_vector_type(8))) short bf16x8;
typedef __attribute__((ext_vector_type(4))) float f32x4;
typedef unsigned long long ull;

__device__ __forceinline__ unsigned short f2bf(float f) {
  union { float f; unsigned u; } v; v.f = f;
  unsigned r = v.u + 0x7fffu + ((v.u >> 16) & 1u);
  return (unsigned short)(r >> 16);
}

__device__ __forceinline__ void gload16(const void* g, void* l) {
  __builtin_amdgcn_global_load_lds(
      (const __attribute__((address_space(1))) unsigned int*)g,
      (__attribute__((address_space(3))) unsigned int*)(unsigned int)(uintptr_t)l,
      16, 0, 0);
}

// ---------------- fused pre-pass: route (blocks 0..1023) + weight transpose (1024..4095) ----------------
__global__ __launch_bounds__(256) void k_pre(
    const float* __restrict__ mu, const int* __restrict__ tok,
    const float* __restrict__ mrw, int* __restrict__ eid,
    int* __restrict__ blockCnt,
    const float* __restrict__ wg, const float* __restrict__ wu,
    const float* __restrict__ wd, unsigned short* __restrict__ WgT,
    unsigned short* __restrict__ WuT, unsigned short* __restrict__ WdT) {
  __shared__ unsigned short lds[64][72];
  int tid = threadIdx.x;

  if (blockIdx.x < 1024) {
    int* cnt = (int*)&lds[0][0];
    if (tid < 8) cnt[tid] = 0;
    int wv = blockIdx.x * 4 + (tid >> 6);
    int t0 = wv * 4;
    int lane = tid & 63;
    const float4* mrw4 = (const float4*)mrw;

    float acc[4][E_NUM];
#pragma unroll
    for (int i = 0; i < 4; i++)
#pragma unroll
      for (int e = 0; e < E_NUM; e++) acc[i][e] = 0.f;

#pragma unroll
    for (int j = 0; j < 4; j++) {
      int idx = lane + 64 * j;
      float4 wr[E_NUM];
#pragma unroll
      for (int e = 0; e < E_NUM; e++) wr[e] = mrw4[e * 256 + idx];
#pragma unroll
      for (int i = 0; i < 4; i++) {
        float4 m = ((const float4*)(mu + (size_t)(t0 + i) * H_DIM))[idx];
#pragma unroll
        for (int e = 0; e < E_NUM; e++)
          acc[i][e] += m.x * wr[e].x + m.y * wr[e].y + m.z * wr[e].z + m.w * wr[e].w;
      }
    }
#pragma unroll
    for (int i = 0; i < 4; i++)
#pragma unroll
      for (int e = 0; e < E_NUM; e++)
#pragma unroll
        for (int off = 32; off >= 1; off >>= 1)
          acc[i][e] += __shfl_xor(acc[i][e], off, 64);

    __syncthreads();
#pragma unroll
    for (int i = 0; i < 4; i++) {
      int tv = tok[t0 + i];
      if (tv < 0) tv = 0;
      if (tv > V_MAX - 1) tv = V_MAX - 1;
      int base = tv & 7;
      int best = 0; float bs = -1e30f;
#pragma unroll
      for (int e = 0; e < E_NUM; e++) {
        float s = acc[i][e] + (e == base ? 10.f : 0.f);
        if (s > bs) { bs = s; best = e; }
      }
      if (lane == i) {
        eid[t0 + i] = best;
        atomicAdd(&cnt[best], 1);
      }
    }
    __syncthreads();
    if (tid < 8) blockCnt[blockIdx.x * 8 + tid] = cnt[tid];
  } else {
    int sel = (blockIdx.x - 1024) >> 10;
    int blk = blockIdx.x & 1023;
    const float* src; unsigned short* dst; int R, C;
    if (sel == 0)      { src = wg; dst = WgT; R = H_DIM; C = IE_DIM; }
    else if (sel == 1) { src = wu; dst = WuT; R = H_DIM; C = IE_DIM; }
    else               { src = wd; dst = WdT; R = IE_DIM; C = H_DIM; }
    int tpe = (R >> 6) * (C >> 6);
    int e = blk / tpe;
    int rem = blk % tpe;
    int tr = rem / (C >> 6);
    int tc = rem % (C >> 6);
    const float* s = src + (size_t)e * R * C;
    unsigned short* d = dst + (size_t)e * R * C;
    int r0 = tid >> 4;
    int c0 = (tid & 15) * 4;
#pragma unroll
    for (int i = 0; i < 4; i++) {
      int r = r0 + i * 16;
      float4 v = *(const float4*)(s + (size_t)(tr * 64 + r) * C + tc * 64 + c0);
      lds[r][c0 + 0] = f2bf(v.x); lds[r][c0 + 1] = f2bf(v.y);
      lds[r][c0 + 2] = f2bf(v.z); lds[r][c0 + 3] = f2bf(v.w);
    }
    __syncthreads();
    int oc = tid >> 2;
    int ob = (tid & 3) * 16;
    unsigned short tmp[16];
#pragma unroll
    for (int i = 0; i < 16; i++) tmp[i] = lds[ob + i][oc];
    uint4* dp = (uint4*)(d + (size_t)(tc * 64 + oc) * R + tr * 64 + ob);
    dp[0] = ((uint4*)tmp)[0];
    dp[1] = ((uint4*)tmp)[1];
  }
}

// ---------------- scan: packed 8x16-bit Hillis-Steele over 1024 blocks ----------------
__global__ __launch_bounds__(1024) void k_scan2(
    const int* __restrict__ blockCnt, int* __restrict__ blockBase,
    int* __restrict__ offsets, int* __restrict__ tileOff) {
  int b = threadIdx.x;
  __shared__ ull s0[1024], s1[1024];
  __shared__ int offL[8];
  const int4* p = (const int4*)(blockCnt + b * 8);
  int4 x0 = p[0], x1 = p[1];
  int c[8] = {x0.x, x0.y, x0.z, x0.w, x1.x, x1.y, x1.z, x1.w};
  ull v0 = (ull)c[0] | ((ull)c[1] << 16) | ((ull)c[2] << 32) | ((ull)c[3] << 48);
  ull v1 = (ull)c[4] | ((ull)c[5] << 16) | ((ull)c[6] << 32) | ((ull)c[7] << 48);
  s0[b] = v0; s1[b] = v1;
  __syncthreads();
  for (int st = 1; st < 1024; st <<= 1) {
    ull a0 = 0, a1 = 0;
    if (b >= st) { a0 = s0[b - st]; a1 = s1[b - st]; }
    __syncthreads();
    v0 += a0; v1 += a1;
    s0[b] = v0; s1[b] = v1;
    __syncthreads();
  }
  if (b == 1023) {
    int tot[8];
#pragma unroll
    for (int e = 0; e < 4; e++) tot[e] = (int)((v0 >> (16 * e)) & 0xFFFF);
#pragma unroll
    for (int e = 0; e < 4; e++) tot[4 + e] = (int)((v1 >> (16 * e)) & 0xFFFF);
    int s = 0, ts = 0;
    for (int e = 0; e < E_NUM; e++) {
      offsets[e] = s; offL[e] = s; tileOff[e] = ts;
      s += tot[e];
      ts += (tot[e] + 255) >> 8;     // 256-row M-tiles
    }
    offsets[E_NUM] = s; tileOff[E_NUM] = ts;
  }
  __syncthreads();
  int be[8];
#pragma unroll
  for (int e = 0; e < 4; e++)
    be[e] = offL[e] + (int)((v0 >> (16 * e)) & 0xFFFF) - c[e];
#pragma unroll
  for (int e = 0; e < 4; e++)
    be[4 + e] = offL[4 + e] + (int)((v1 >> (16 * e)) & 0xFFFF) - c[4 + e];
  int4* q = (int4*)(blockBase + b * 8);
  q[0] = make_int4(be[0], be[1], be[2], be[3]);
  q[1] = make_int4(be[4], be[5], be[6], be[7]);
}

// ---------------- gather: deterministic rank, no atomics ----------------
__global__ __launch_bounds__(256) void k_gather(
    const float* __restrict__ hs, const int* __restrict__ eid,
    const int* __restrict__ blockBase, int* __restrict__ tokofrow,
    unsigned short* __restrict__ Xs) {
  int b = blockIdx.x;
  int tid = threadIdx.x;
  __shared__ int eL[16];
  __shared__ int posL[16];
  if (tid < 16) eL[tid] = eid[b * 16 + tid];
  __syncthreads();
  if (tid < 16) {
    int e = eL[tid];
    int r = 0;
    for (int j = 0; j < tid; j++) r += (eL[j] == e);
    int pos = blockBase[b * 8 + e] + r;
    posL[tid] = pos;
    tokofrow[pos] = b * 16 + tid;
  }
  __syncthreads();
  int w = tid >> 6, lane = tid & 63;
#pragma unroll
  for (int i = 0; i < 4; i++) {
    int li = w * 4 + i;
    int t = b * 16 + li;
    int pos = posL[li];
    const float4* src = (const float4*)(hs + (size_t)t * H_DIM);
    unsigned short* drow = Xs + (size_t)pos * H_DIM;
#pragma unroll
    for (int j = 0; j < 4; j++) {
      float4 v = src[lane + 64 * j];
      ushort4 bb;
      bb.x = f2bf(v.x); bb.y = f2bf(v.y); bb.z = f2bf(v.z); bb.w = f2bf(v.w);
      *(ushort4*)(drow + (lane + 64 * j) * 4) = bb;
    }
  }
}

// ---------------- GEMM1 (8-phase): h = silu(X Wg) * (X Wu), bf16 out ----------------
// BM=256, BN=128(dual), BK=64. 8 waves 4Mx2N, wave tile 64x64 for g AND u.
// LDS 128KB, 2 dbuf, 4 phases/K-tile, counted vmcnt(2) once per K-tile.
__global__ __launch_bounds__(512, 1) void k_gemm1(
    const unsigned short* __restrict__ Xs,
    const unsigned short* __restrict__ WgT,
    const unsigned short* __restrict__ WuT,
    unsigned short* __restrict__ Hb,
    const int* __restrict__ offsets, const int* __restrict__ tileOff) {
  // bijective XCD swizzle for nwg=284: q=35, r=4
  int bid0 = blockIdx.x;
  int xcd = bid0 & 7, seq = bid0 >> 3;
  int wg = (xcd < 4 ? xcd * 36 : 144 + (xcd - 4) * 35) + seq;
  int nt = wg & 3;          // 4 n-tiles of 128
  int mlin = wg >> 2;
  if (mlin >= tileOff[E_NUM]) return;
  int e = 0;
#pragma unroll
  for (int i = 1; i < E_NUM; i++)
    if (mlin >= tileOff[i]) e = i;
  int mtile = mlin - tileOff[e];
  int segStart = offsets[e], segEnd = offsets[e + 1];
  int M = segEnd - segStart;

  __shared__ unsigned short Alds[2][256 * 64];   // 64KB
  __shared__ unsigned short Bglds[2][128 * 64];  // 32KB
  __shared__ unsigned short Bulds[2][128 * 64];  // 32KB

  int tid = threadIdx.x;
  int lane = tid & 63;
  int w = tid >> 6;
  int wm = w >> 1;        // 0..3
  int wn = w & 1;         // 0..1
  int r0 = lane & 15;
  int kcb = lane >> 4;    // 0..3

  f32x4 accg[4][4], accu[4][4];
#pragma unroll
  for (int i = 0; i < 4; i++)
#pragma unroll
    for (int j = 0; j < 4; j++) {
      accg[i][j] = (f32x4)(0.f);
      accu[i][j] = (f32x4)(0.f);
    }

  // staging sources: A 4 slots/thread, Bg 2, Bu 2 (slot s -> row s>>3, chunk (s&7)^(row&7))
  const unsigned short* Asrc[4];
#pragma unroll
  for (int i = 0; i < 4; i++) {
    int s = tid + i * 512;
    int row = s >> 3;
    int ch = (s & 7) ^ (row & 7);
    int gr = mtile * 256 + row; if (gr > M - 1) gr = M - 1;
    Asrc[i] = Xs + (size_t)(segStart + gr) * H_DIM + ch * 8;
  }
  const unsigned short* Bgsrc[2];
  const unsigned short* Busrc[2];
#pragma unroll
  for (int i = 0; i < 2; i++) {
    int s = tid + i * 512;
    int row = s >> 3;
    int ch = (s & 7) ^ (row & 7);
    Bgsrc[i] = WgT + (size_t)e * IE_DIM * H_DIM + (size_t)(nt * 128 + row) * H_DIM + ch * 8;
    Busrc[i] = WuT + (size_t)e * IE_DIM * H_DIM + (size_t)(nt * 128 + row) * H_DIM + ch * 8;
  }

#define GLA(i, kt, buf) gload16(Asrc[i] + (kt) * 64, (char*)Alds[buf] + (tid + (i) * 512) * 16)
#define GLG(i, kt, buf) gload16(Bgsrc[i] + (kt) * 64, (char*)Bglds[buf] + (tid + (i) * 512) * 16)
#define GLU(i, kt, buf) gload16(Busrc[i] + (kt) * 64, (char*)Bulds[buf] + (tid + (i) * 512) * 16)

  // ds_read byte offsets: row*128 + ((c ^ (row&7))<<4), c = ks*4 + kcb
  int aoff[4][2], boff[4][2];
#pragma unroll
  for (int mf = 0; mf < 4; mf++) {
    int row = wm * 64 + mf * 16 + r0;
#pragma unroll
    for (int ks = 0; ks < 2; ks++) {
      int c = ks * 4 + kcb;
      aoff[mf][ks] = row * 128 + ((c ^ (row & 7)) << 4);
    }
  }
#pragma unroll
  for (int nf = 0; nf < 4; nf++) {
    int row = wn * 64 + nf * 16 + r0;
#pragma unroll
    for (int ks = 0; ks < 2; ks++) {
      int c = ks * 4 + kcb;
      boff[nf][ks] = row * 128 + ((c ^ (row & 7)) << 4);
    }
  }

  const int NT = H_DIM / 64;   // 16
  // prologue: stage kt=0 into buf0
  GLA(0, 0, 0); GLA(1, 0, 0); GLA(2, 0, 0); GLA(3, 0, 0);
  GLG(0, 0, 0); GLG(1, 0, 0); GLU(0, 0, 0); GLU(1, 0, 0);

  bf16x8 a0[2][2], a1[2][2], bb[4][2];

  for (int kt = 0; kt < NT; kt++) {
    int buf = kt & 1, nbuf = buf ^ 1;
    int ktn = (kt + 1 < NT) ? kt + 1 : 0;
    const char* Ab = (const char*)Alds[buf];
    const char* Bgb = (const char*)Bglds[buf];
    const char* Bub = (const char*)Bulds[buf];

    // ---- P1: stage A0,A1(kt+1); wait kt loads; read a0+bg; mfma g m0/m1 ----
    GLA(0, ktn, nbuf); GLA(1, ktn, nbuf);
    asm volatile("s_waitcnt vmcnt(2)" ::: "memory");
    __builtin_amdgcn_s_barrier();
#pragma unroll
    for (int mf = 0; mf < 2; mf++)
#pragma unroll
      for (int ks = 0; ks < 2; ks++)
        a0[mf][ks] = *(const bf16x8*)(Ab + aoff[mf][ks]);
#pragma unroll
    for (int nf = 0; nf < 4; nf++)
#pragma unroll
      for (int ks = 0; ks < 2; ks++)
        bb[nf][ks] = *(const bf16x8*)(Bgb + boff[nf][ks]);
    asm volatile("s_waitcnt lgkmcnt(0)" ::: "memory");
    __builtin_amdgcn_sched_barrier(0);
    __builtin_amdgcn_s_setprio(1);
#pragma unroll
    for (int mf = 0; mf < 2; mf++)
#pragma unroll
      for (int nf = 0; nf < 4; nf++)
#pragma unroll
        for (int ks = 0; ks < 2; ks++)
          accg[mf][nf] = __builtin_amdgcn_mfma_f32_16x16x32_bf16(
              a0[mf][ks], bb[nf][ks], accg[mf][nf], 0, 0, 0);
    __builtin_amdgcn_s_setprio(0);
    __builtin_amdgcn_s_barrier();

    // ---- P2: stage A2,A3; read a1; mfma g m2/m3 ----
    GLA(2, ktn, nbuf); GLA(3, ktn, nbuf);
#pragma unroll
    for (int mf = 0; mf < 2; mf++)
#pragma unroll
      for (int ks = 0; ks < 2; ks++)
        a1[mf][ks] = *(const bf16x8*)(Ab + aoff[2 + mf][ks]);
    __builtin_amdgcn_s_barrier();
    asm volatile("s_waitcnt lgkmcnt(0)" ::: "memory");
    __builtin_amdgcn_sched_barrier(0);
    __builtin_amdgcn_s_setprio(1);
#pragma unroll
    for (int mf = 0; mf < 2; mf++)
#pragma unroll
      for (int nf = 0; nf < 4; nf++)
#pragma unroll
        for (int ks = 0; ks < 2; ks++)
          accg[2 + mf][nf] = __builtin_amdgcn_mfma_f32_16x16x32_bf16(
              a1[mf][ks], bb[nf][ks], accg[2 + mf][nf], 0, 0, 0);
    __builtin_amdgcn_s_setprio(0);
    __builtin_amdgcn_s_barrier();

    // ---- P3: stage Bg0,Bg1; read bu (overwrite bb); mfma u m0/m1 ----
    GLG(0, ktn, nbuf); GLG(1, ktn, nbuf);
#pragma unroll
    for (int nf = 0; nf < 4; nf++)
#pragma unroll
      for (int ks = 0; ks < 2; ks++)
        bb[nf][ks] = *(const bf16x8*)(Bub + boff[nf][ks]);
    __builtin_amdgcn_s_barrier();
    asm volatile("s_waitcnt lgkmcnt(0)" ::: "memory");
    __builtin_amdgcn_sched_barrier(0);
    __builtin_amdgcn_s_setprio(1);
#pragma unroll
    for (int mf = 0; mf < 2; mf++)
#pragma unroll
      for (int nf = 0; nf < 4; nf++)
#pragma unroll
        for (int ks = 0; ks < 2; ks++)
          accu[mf][nf] = __builtin_amdgcn_mfma_f32_16x16x32_bf16(
              a0[mf][ks], bb[nf][ks], accu[mf][nf], 0, 0, 0);
    __builtin_amdgcn_s_setprio(0);
    __builtin_amdgcn_s_barrier();

    // ---- P4: stage Bu0,Bu1; mfma u m2/m3 ----
    GLU(0, ktn, nbuf); GLU(1, ktn, nbuf);
    __builtin_amdgcn_s_barrier();
    __builtin_amdgcn_s_setprio(1);
#pragma unroll
    for (int mf = 0; mf < 2; mf++)
#pragma unroll
      for (int nf = 0; nf < 4; nf++)
#pragma unroll
        for (int ks = 0; ks < 2; ks++)
          accu[2 + mf][nf] = __builtin_amdgcn_mfma_f32_16x16x32_bf16(
              a1[mf][ks], bb[nf][ks], accu[2 + mf][nf], 0, 0, 0);
    __builtin_amdgcn_s_setprio(0);
    __builtin_amdgcn_s_barrier();
  }
  asm volatile("s_waitcnt vmcnt(0)" ::: "memory");
#undef GLA
#undef GLG
#undef GLU

  int rowBase = segStart + mtile * 256 + wm * 64;
#pragma unroll
  for (int mf = 0; mf < 4; mf++)
#pragma unroll
    for (int nf = 0; nf < 4; nf++) {
      int col = nt * 128 + wn * 64 + nf * 16 + r0;
#pragma unroll
      for (int j = 0; j < 4; j++) {
        int r = rowBase + mf * 16 + (lane >> 4) * 4 + j;
        if (r < segEnd) {
          float g = accg[mf][nf][j];
          float u = accu[mf][nf][j];
          float h = (g / (1.f + __expf(-g))) * u;
          Hb[(size_t)r * IE_DIM + col] = f2bf(h);
        }
      }
    }
}

// ---------------- GEMM2 (8-phase): out[tok] = h Wd, fp32 scatter ----------------
// BM=256, BN=256, BK=64. 8 waves 4Mx2N, wave tile 64x128. LDS 128KB, 2 dbuf.
__global__ __launch_bounds__(512, 1) void k_gemm2(
    const unsigned short* __restrict__ Hb,
    const unsigned short* __restrict__ WdT,
    float* __restrict__ out,
    const int* __restrict__ offsets, const int* __restrict__ tileOff,
    const int* __restrict__ tokofrow) {
  int bid0 = blockIdx.x;
  int xcd = bid0 & 7, seq = bid0 >> 3;
  int wg = (xcd < 4 ? xcd * 36 : 144 + (xcd - 4) * 35) + seq;
  int nt = wg & 3;          // 4 n-tiles of 256
  int mlin = wg >> 2;
  if (mlin >= tileOff[E_NUM]) return;
  int e = 0;
#pragma unroll
  for (int i = 1; i < E_NUM; i++)
    if (mlin >= tileOff[i]) e = i;
  int mtile = mlin - tileOff[e];
  int segStart = offsets[e], segEnd = offsets[e + 1];
  int M = segEnd - segStart;

  __shared__ unsigned short Alds[2][256 * 64];   // 64KB
  __shared__ unsigned short Blds[2][256 * 64];   // 64KB

  int tid = threadIdx.x;
  int lane = tid & 63;
  int w = tid >> 6;
  int wm = w >> 1;        // 0..3
  int wn = w & 1;         // 0..1
  int r0 = lane & 15;
  int kcb = lane >> 4;

  f32x4 acc[4][8];
#pragma unroll
  for (int i = 0; i < 4; i++)
#pragma unroll
    for (int j = 0; j < 8; j++) acc[i][j] = (f32x4)(0.f);

  const unsigned short* Asrc[4];
  const unsigned short* Bsrc[4];
#pragma unroll
  for (int i = 0; i < 4; i++) {
    int s = tid + i * 512;
    int row = s >> 3;
    int ch = (s & 7) ^ (row & 7);
    int gr = mtile * 256 + row; if (gr > M - 1) gr = M - 1;
    Asrc[i] = Hb + (size_t)(segStart + gr) * IE_DIM + ch * 8;
    Bsrc[i] = WdT + (size_t)e * H_DIM * IE_DIM + (size_t)(nt * 256 + row) * IE_DIM + ch * 8;
  }

#define GLA2(i, kt, buf) gload16(Asrc[i] + (kt) * 64, (char*)Alds[buf] + (tid + (i) * 512) * 16)
#define GLB2(i, kt, buf) gload16(Bsrc[i] + (kt) * 64, (char*)Blds[buf] + (tid + (i) * 512) * 16)

  int aoff[4][2], boff[8][2];
#pragma unroll
  for (int mf = 0; mf < 4; mf++) {
    int row = wm * 64 + mf * 16 + r0;
#pragma unroll
    for (int ks = 0; ks < 2; ks++) {
      int c = ks * 4 + kcb;
      aoff[mf][ks] = row * 128 + ((c ^ (row & 7)) << 4);
    }
  }
#pragma unroll
  for (int nf = 0; nf < 8; nf++) {
    int row = wn * 128 + nf * 16 + r0;
#pragma unroll
    for (int ks = 0; ks < 2; ks++) {
      int c = ks * 4 + kcb;
      boff[nf][ks] = row * 128 + ((c ^ (row & 7)) << 4);
    }
  }

  const int NT = IE_DIM / 64;   // 8
  GLA2(0, 0, 0); GLA2(1, 0, 0); GLA2(2, 0, 0); GLA2(3, 0, 0);
  GLB2(0, 0, 0); GLB2(1, 0, 0); GLB2(2, 0, 0); GLB2(3, 0, 0);

  bf16x8 a0[2][2], a1[2][2], bb[4][2];

  for (int kt = 0; kt < NT; kt++) {
    int buf = kt & 1, nbuf = buf ^ 1;
    int ktn = (kt + 1 < NT) ? kt + 1 : 0;
    const char* Ab = (const char*)Alds[buf];
    const char* Bb = (const char*)Blds[buf];

    // ---- P1: stage A0,A1; wait; read a0 + b(nh0); mfma (m01, nh0) ----
    GLA2(0, ktn, nbuf); GLA2(1, ktn, nbuf);
    asm volatile("s_waitcnt vmcnt(2)" ::: "memory");
    __builtin_amdgcn_s_barrier();
#pragma unroll
    for (int mf = 0; mf < 2; mf++)
#pragma unroll
      for (int ks = 0; ks < 2; ks++)
        a0[mf][ks] = *(const bf16x8*)(Ab + aoff[mf][ks]);
#pragma unroll
    for (int nf = 0; nf < 4; nf++)
#pragma unroll
      for (int ks = 0; ks < 2; ks++)
        bb[nf][ks] = *(const bf16x8*)(Bb + boff[nf][ks]);
    asm volatile("s_waitcnt lgkmcnt(0)" ::: "memory");
    __builtin_amdgcn_sched_barrier(0);
    __builtin_amdgcn_s_setprio(1);
#pragma unroll
    for (int mf = 0; mf < 2; mf++)
#pragma unroll
      for (int nf = 0; nf < 4; nf++)
#pragma unroll
        for (int ks = 0; ks < 2; ks++)
          acc[mf][nf] = __builtin_amdgcn_mfma_f32_16x16x32_bf16(
              a0[mf][ks], bb[nf][ks], acc[mf][nf], 0, 0, 0);
    __builtin_amdgcn_s_setprio(0);
    __builtin_amdgcn_s_barrier();

    // ---- P2: stage A2,A3; read a1; mfma (m23, nh0) ----
    GLA2(2, ktn, nbuf); GLA2(3, ktn, nbuf);
#pragma unroll
    for (int mf = 0; mf < 2; mf++)
#pragma unroll
      for (int ks = 0; ks < 2; ks++)
        a1[mf][ks] = *(const bf16x8*)(Ab + aoff[2 + mf][ks]);
    __builtin_amdgcn_s_barrier();
    asm volatile("s_waitcnt lgkmcnt(0)" ::: "memory");
    __builtin_amdgcn_sched_barrier(0);
    __builtin_amdgcn_s_setprio(1);
#pragma unroll
    for (int mf = 0; mf < 2; mf++)
#pragma unroll
      for (int nf = 0; nf < 4; nf++)
#pragma unroll
        for (int ks = 0; ks < 2; ks++)
          acc[2 + mf][nf] = __builtin_amdgcn_mfma_f32_16x16x32_bf16(
              a1[mf][ks], bb[nf][ks], acc[2 + mf][nf], 0, 0, 0);
    __builtin_amdgcn_s_setprio(0);
    __builtin_amdgcn_s_barrier();

    // ---- P3: stage B0,B1; read b(nh1); mfma (m01, nh1) ----
    GLB2(0, ktn, nbuf); GLB2(1, ktn, nbuf);
#pragma unroll
    for (int nf = 0; nf < 4; nf++)
#pragma unroll
      for (int ks = 0; ks < 2; ks++)
        bb[nf][ks] = *(const bf16x8*)(Bb + boff[4 + nf][ks]);
    __builtin_amdgcn_s_barrier();
    asm volatile("s_waitcnt lgkmcnt(0)" ::: "memory");
    __builtin_amdgcn_sched_barrier(0);
    __builtin_amdgcn_s_setprio(1);
#pragma unroll
    for (int mf = 0; mf < 2; mf++)
#pragma unroll
      for (int nf = 0; nf < 4; nf++)
#pragma unroll
        for (int ks = 0; ks < 2; ks++)
          acc[mf][4 + nf] = __builtin_amdgcn_mfma_f32_16x16x32_bf16(
              a0[mf][ks], bb[nf][ks], acc[mf][4 + nf], 0, 0, 0);
    __builtin_amdgcn_s_setprio(0);
    __builtin_amdgcn_s_barrier();

    // ---- P4: stage B2,B3; mfma (m23, nh1) ----
    GLB2(2, ktn, nbuf); GLB2(3, ktn, nbuf);
    __builtin_amdgcn_s_barrier();
    __builtin_amdgcn_s_setprio(1);
#pragma unroll
    for (int mf = 0; mf < 2; mf++)
#pragma unroll
      for (int nf = 0; nf < 4; nf++)
#pragma unroll
        for (int ks = 0; ks < 2; ks++)
          acc[2 + mf][4 + nf] = __builtin_amdgcn_mfma_f32_16x16x32_bf16(
              a1[mf][ks], bb[nf][ks], acc[2 + mf][4 + nf], 0, 0, 0);
    __builtin_amdgcn_s_setprio(0);
    __builtin_amdgcn_s_barrier();
  }
  asm volatile("s_waitcnt vmcnt(0)" ::: "memory");
#undef GLA2
#undef GLB2

  int rowBase = segStart + mtile * 256 + wm * 64;
#pragma unroll
  for (int mf = 0; mf < 4; mf++)
#pragma unroll
    for (int nf = 0; nf < 8; nf++) {
      int col = nt * 256 + wn * 128 + nf * 16 + r0;
#pragma unroll
      for (int j = 0; j < 4; j++) {
        int r = rowBase + mf * 16 + (lane >> 4) * 4 + j;
        if (r < segEnd) {
          int t = tokofrow[r];
          out[(size_t)t * H_DIM + col] = acc[mf][nf][j];
        }
      }
    }
}

// ---------------- workspace layout (bytes) ----------------
#define WS_XS    ((size_t)0)             // 32MB
#define WS_WGT   ((size_t)33554432)      // 8MB
#define WS_WUT   ((size_t)41943040)      // 8MB
#define WS_WDT   ((size_t)50331648)      // 8MB
#define WS_HB    ((size_t)58720256)      // 16MB
#define WS_EID   ((size_t)75497472)      // 64KB
#define WS_TOK   ((size_t)75563008)      // 64KB
#define WS_OFF   ((size_t)75628544)      // offsets/tileOff (1KB)
#define WS_BC    ((size_t)75629568)      // blockCnt 32KB
#define WS_BB    ((size_t)75662336)      // blockBase 32KB

extern "C" void kernel_launch(void* const* d_in, const int* in_sizes, int n_in,
                              void* d_out, int out_size, void* d_ws, size_t ws_size,
                              hipStream_t stream) {
  const float* hs  = (const float*)d_in[0];
  const int*   tok = (const int*)d_in[1];
  const float* mu  = (const float*)d_in[2];
  const float* wg  = (const float*)d_in[3];
  const float* wu  = (const float*)d_in[4];
  const float* wd  = (const float*)d_in[5];
  const float* mrw = (const float*)d_in[6];
  float* out = (float*)d_out;
  char* ws = (char*)d_ws;

  unsigned short* Xs  = (unsigned short*)(ws + WS_XS);
  unsigned short* WgT = (unsigned short*)(ws + WS_WGT);
  unsigned short* WuT = (unsigned short*)(ws + WS_WUT);
  unsigned short* WdT = (unsigned short*)(ws + WS_WDT);
  unsigned short* Hb  = (unsigned short*)(ws + WS_HB);
  int* eid      = (int*)(ws + WS_EID);
  int* tokofrow = (int*)(ws + WS_TOK);
  int* offsets  = (int*)(ws + WS_OFF);   // [9]
  int* tileOff  = offsets + 16;          // [9]
  int* blockCnt = (int*)(ws + WS_BC);    // [1024][8]
  int* blockBase= (int*)(ws + WS_BB);    // [1024][8]

  k_pre<<<4096, 256, 0, stream>>>(mu, tok, mrw, eid, blockCnt,
                                  wg, wu, wd, WgT, WuT, WdT);
  k_scan2<<<1, 1024, 0, stream>>>(blockCnt, blockBase, offsets, tileOff);
  k_gather<<<1024, 256, 0, stream>>>(hs, eid, blockBase, tokofrow, Xs);
  // worst-case M-tiles(256) = ceil(T/256) + (E-1) = 71; x4 n-tiles = 284
  k_gemm1<<<284, 512, 0, stream>>>(Xs, WgT, WuT, Hb, offsets, tileOff);
  k_gemm2<<<284, 512, 0, stream>>>(Hb, WdT, out, offsets, tileOff, tokofrow);
}

// Round 12
// 169.014 us; speedup vs baseline: 1.6332x; 1.1193x over previous
//
#include <hip/hip_runtime.h>
#include <stdint.h>

// Problem constants
#define T_TOK   16384      // B*S
#define H_DIM   1024
#define IE_DIM  512
#define E_NUM   8
#define V_MAX   100000

typedef __attribute__((ext_vector_type(8))) short bf16x8;
typedef __attribute__((ext_vector_type(4))) float f32x4;
typedef unsigned long long ull;

__device__ __forceinline__ unsigned short f2bf(float f) {
  union { float f; unsigned u; } v; v.f = f;
  unsigned r = v.u + 0x7fffu + ((v.u >> 16) & 1u);
  return (unsigned short)(r >> 16);
}

__device__ __forceinline__ void gload16(const void* g, void* l) {
  __builtin_amdgcn_global_load_lds(
      (const __attribute__((address_space(1))) unsigned int*)g,
      (__attribute__((address_space(3))) unsigned int*)(unsigned int)(uintptr_t)l,
      16, 0, 0);
}

// ---------------- fused pre-pass: route (blocks 0..1023) + weight transpose (1024..4095) ----------------
__global__ __launch_bounds__(256) void k_pre(
    const float* __restrict__ mu, const int* __restrict__ tok,
    const float* __restrict__ mrw, int* __restrict__ eid,
    int* __restrict__ blockCnt,
    const float* __restrict__ wg, const float* __restrict__ wu,
    const float* __restrict__ wd, unsigned short* __restrict__ WgT,
    unsigned short* __restrict__ WuT, unsigned short* __restrict__ WdT) {
  __shared__ unsigned short lds[64][72];
  int tid = threadIdx.x;

  if (blockIdx.x < 1024) {
    int* cnt = (int*)&lds[0][0];
    if (tid < 8) cnt[tid] = 0;
    int wv = blockIdx.x * 4 + (tid >> 6);
    int t0 = wv * 4;
    int lane = tid & 63;
    const float4* mrw4 = (const float4*)mrw;

    float acc[4][E_NUM];
#pragma unroll
    for (int i = 0; i < 4; i++)
#pragma unroll
      for (int e = 0; e < E_NUM; e++) acc[i][e] = 0.f;

#pragma unroll
    for (int j = 0; j < 4; j++) {
      int idx = lane + 64 * j;
      float4 wr[E_NUM];
#pragma unroll
      for (int e = 0; e < E_NUM; e++) wr[e] = mrw4[e * 256 + idx];
#pragma unroll
      for (int i = 0; i < 4; i++) {
        float4 m = ((const float4*)(mu + (size_t)(t0 + i) * H_DIM))[idx];
#pragma unroll
        for (int e = 0; e < E_NUM; e++)
          acc[i][e] += m.x * wr[e].x + m.y * wr[e].y + m.z * wr[e].z + m.w * wr[e].w;
      }
    }
#pragma unroll
    for (int i = 0; i < 4; i++)
#pragma unroll
      for (int e = 0; e < E_NUM; e++)
#pragma unroll
        for (int off = 32; off >= 1; off >>= 1)
          acc[i][e] += __shfl_xor(acc[i][e], off, 64);

    __syncthreads();
#pragma unroll
    for (int i = 0; i < 4; i++) {
      int tv = tok[t0 + i];
      if (tv < 0) tv = 0;
      if (tv > V_MAX - 1) tv = V_MAX - 1;
      int base = tv & 7;
      int best = 0; float bs = -1e30f;
#pragma unroll
      for (int e = 0; e < E_NUM; e++) {
        float s = acc[i][e] + (e == base ? 10.f : 0.f);
        if (s > bs) { bs = s; best = e; }
      }
      if (lane == i) {
        eid[t0 + i] = best;
        atomicAdd(&cnt[best], 1);
      }
    }
    __syncthreads();
    if (tid < 8) blockCnt[blockIdx.x * 8 + tid] = cnt[tid];
  } else {
    int sel = (blockIdx.x - 1024) >> 10;
    int blk = blockIdx.x & 1023;
    const float* src; unsigned short* dst; int R, C;
    if (sel == 0)      { src = wg; dst = WgT; R = H_DIM; C = IE_DIM; }
    else if (sel == 1) { src = wu; dst = WuT; R = H_DIM; C = IE_DIM; }
    else               { src = wd; dst = WdT; R = IE_DIM; C = H_DIM; }
    int tpe = (R >> 6) * (C >> 6);
    int e = blk / tpe;
    int rem = blk % tpe;
    int tr = rem / (C >> 6);
    int tc = rem % (C >> 6);
    const float* s = src + (size_t)e * R * C;
    unsigned short* d = dst + (size_t)e * R * C;
    int r0 = tid >> 4;
    int c0 = (tid & 15) * 4;
#pragma unroll
    for (int i = 0; i < 4; i++) {
      int r = r0 + i * 16;
      float4 v = *(const float4*)(s + (size_t)(tr * 64 + r) * C + tc * 64 + c0);
      lds[r][c0 + 0] = f2bf(v.x); lds[r][c0 + 1] = f2bf(v.y);
      lds[r][c0 + 2] = f2bf(v.z); lds[r][c0 + 3] = f2bf(v.w);
    }
    __syncthreads();
    int oc = tid >> 2;
    int ob = (tid & 3) * 16;
    unsigned short tmp[16];
#pragma unroll
    for (int i = 0; i < 16; i++) tmp[i] = lds[ob + i][oc];
    uint4* dp = (uint4*)(d + (size_t)(tc * 64 + oc) * R + tr * 64 + ob);
    dp[0] = ((uint4*)tmp)[0];
    dp[1] = ((uint4*)tmp)[1];
  }
}

// ---------------- scan: packed 8x16-bit Hillis-Steele over 1024 blocks ----------------
__global__ __launch_bounds__(1024) void k_scan2(
    const int* __restrict__ blockCnt, int* __restrict__ blockBase,
    int* __restrict__ offsets, int* __restrict__ tileOff,
    int* __restrict__ tileOff128) {
  int b = threadIdx.x;
  __shared__ ull s0[1024], s1[1024];
  __shared__ int offL[8];
  const int4* p = (const int4*)(blockCnt + b * 8);
  int4 x0 = p[0], x1 = p[1];
  int c[8] = {x0.x, x0.y, x0.z, x0.w, x1.x, x1.y, x1.z, x1.w};
  ull v0 = (ull)c[0] | ((ull)c[1] << 16) | ((ull)c[2] << 32) | ((ull)c[3] << 48);
  ull v1 = (ull)c[4] | ((ull)c[5] << 16) | ((ull)c[6] << 32) | ((ull)c[7] << 48);
  s0[b] = v0; s1[b] = v1;
  __syncthreads();
  for (int st = 1; st < 1024; st <<= 1) {
    ull a0 = 0, a1 = 0;
    if (b >= st) { a0 = s0[b - st]; a1 = s1[b - st]; }
    __syncthreads();
    v0 += a0; v1 += a1;
    s0[b] = v0; s1[b] = v1;
    __syncthreads();
  }
  if (b == 1023) {
    int tot[8];
#pragma unroll
    for (int e = 0; e < 4; e++) tot[e] = (int)((v0 >> (16 * e)) & 0xFFFF);
#pragma unroll
    for (int e = 0; e < 4; e++) tot[4 + e] = (int)((v1 >> (16 * e)) & 0xFFFF);
    int s = 0, ts = 0, ts2 = 0;
    for (int e = 0; e < E_NUM; e++) {
      offsets[e] = s; offL[e] = s;
      tileOff[e] = ts; tileOff128[e] = ts2;
      s += tot[e];
      ts += (tot[e] + 255) >> 8;     // 256-row M-tiles (gemm1)
      ts2 += (tot[e] + 127) >> 7;    // 128-row M-tiles (gemm2)
    }
    offsets[E_NUM] = s; tileOff[E_NUM] = ts; tileOff128[E_NUM] = ts2;
  }
  __syncthreads();
  int be[8];
#pragma unroll
  for (int e = 0; e < 4; e++)
    be[e] = offL[e] + (int)((v0 >> (16 * e)) & 0xFFFF) - c[e];
#pragma unroll
  for (int e = 0; e < 4; e++)
    be[4 + e] = offL[4 + e] + (int)((v1 >> (16 * e)) & 0xFFFF) - c[4 + e];
  int4* q = (int4*)(blockBase + b * 8);
  q[0] = make_int4(be[0], be[1], be[2], be[3]);
  q[1] = make_int4(be[4], be[5], be[6], be[7]);
}

// ---------------- gather: deterministic rank, no atomics ----------------
__global__ __launch_bounds__(256) void k_gather(
    const float* __restrict__ hs, const int* __restrict__ eid,
    const int* __restrict__ blockBase, int* __restrict__ tokofrow,
    unsigned short* __restrict__ Xs) {
  int b = blockIdx.x;
  int tid = threadIdx.x;
  __shared__ int eL[16];
  __shared__ int posL[16];
  if (tid < 16) eL[tid] = eid[b * 16 + tid];
  __syncthreads();
  if (tid < 16) {
    int e = eL[tid];
    int r = 0;
    for (int j = 0; j < tid; j++) r += (eL[j] == e);
    int pos = blockBase[b * 8 + e] + r;
    posL[tid] = pos;
    tokofrow[pos] = b * 16 + tid;
  }
  __syncthreads();
  int w = tid >> 6, lane = tid & 63;
#pragma unroll
  for (int i = 0; i < 4; i++) {
    int li = w * 4 + i;
    int t = b * 16 + li;
    int pos = posL[li];
    const float4* src = (const float4*)(hs + (size_t)t * H_DIM);
    unsigned short* drow = Xs + (size_t)pos * H_DIM;
#pragma unroll
    for (int j = 0; j < 4; j++) {
      float4 v = src[lane + 64 * j];
      ushort4 bb;
      bb.x = f2bf(v.x); bb.y = f2bf(v.y); bb.z = f2bf(v.z); bb.w = f2bf(v.w);
      *(ushort4*)(drow + (lane + 64 * j) * 4) = bb;
    }
  }
}

// ---------------- GEMM1 (8-phase, fixed wait): h = silu(X Wg) * (X Wu) ----------------
// BM=256, BN=128(dual), BK=64. 8 waves 4Mx2N. LDS 128KB, 2 dbuf.
// Per K-tile: barrier; issue all 8 stage loads; vmcnt(8) (full-iter distance);
// barrier; 4 {ds_read, lgkmcnt, MFMA} phases.
__global__ __launch_bounds__(512, 1) void k_gemm1(
    const unsigned short* __restrict__ Xs,
    const unsigned short* __restrict__ WgT,
    const unsigned short* __restrict__ WuT,
    unsigned short* __restrict__ Hb,
    const int* __restrict__ offsets, const int* __restrict__ tileOff) {
  // bijective XCD swizzle for nwg=284: q=35, r=4
  int bid0 = blockIdx.x;
  int xcd = bid0 & 7, seq = bid0 >> 3;
  int wg = (xcd < 4 ? xcd * 36 : 144 + (xcd - 4) * 35) + seq;
  int nt = wg & 3;          // 4 n-tiles of 128
  int mlin = wg >> 2;
  if (mlin >= tileOff[E_NUM]) return;
  int e = 0;
#pragma unroll
  for (int i = 1; i < E_NUM; i++)
    if (mlin >= tileOff[i]) e = i;
  int mtile = mlin - tileOff[e];
  int segStart = offsets[e], segEnd = offsets[e + 1];
  int M = segEnd - segStart;

  __shared__ unsigned short Alds[2][256 * 64];   // 64KB
  __shared__ unsigned short Bglds[2][128 * 64];  // 32KB
  __shared__ unsigned short Bulds[2][128 * 64];  // 32KB

  int tid = threadIdx.x;
  int lane = tid & 63;
  int w = tid >> 6;
  int wm = w >> 1;        // 0..3
  int wn = w & 1;         // 0..1
  int r0 = lane & 15;
  int kcb = lane >> 4;    // 0..3

  f32x4 accg[4][4], accu[4][4];
#pragma unroll
  for (int i = 0; i < 4; i++)
#pragma unroll
    for (int j = 0; j < 4; j++) {
      accg[i][j] = (f32x4)(0.f);
      accu[i][j] = (f32x4)(0.f);
    }

  const unsigned short* Asrc[4];
#pragma unroll
  for (int i = 0; i < 4; i++) {
    int s = tid + i * 512;
    int row = s >> 3;
    int ch = (s & 7) ^ (row & 7);
    int gr = mtile * 256 + row; if (gr > M - 1) gr = M - 1;
    Asrc[i] = Xs + (size_t)(segStart + gr) * H_DIM + ch * 8;
  }
  const unsigned short* Bgsrc[2];
  const unsigned short* Busrc[2];
#pragma unroll
  for (int i = 0; i < 2; i++) {
    int s = tid + i * 512;
    int row = s >> 3;
    int ch = (s & 7) ^ (row & 7);
    Bgsrc[i] = WgT + (size_t)e * IE_DIM * H_DIM + (size_t)(nt * 128 + row) * H_DIM + ch * 8;
    Busrc[i] = WuT + (size_t)e * IE_DIM * H_DIM + (size_t)(nt * 128 + row) * H_DIM + ch * 8;
  }

#define GLA(i, kt, buf) gload16(Asrc[i] + (kt) * 64, (char*)Alds[buf] + (tid + (i) * 512) * 16)
#define GLG(i, kt, buf) gload16(Bgsrc[i] + (kt) * 64, (char*)Bglds[buf] + (tid + (i) * 512) * 16)
#define GLU(i, kt, buf) gload16(Busrc[i] + (kt) * 64, (char*)Bulds[buf] + (tid + (i) * 512) * 16)

  int aoff[4][2], boff[4][2];
#pragma unroll
  for (int mf = 0; mf < 4; mf++) {
    int row = wm * 64 + mf * 16 + r0;
#pragma unroll
    for (int ks = 0; ks < 2; ks++) {
      int c = ks * 4 + kcb;
      aoff[mf][ks] = row * 128 + ((c ^ (row & 7)) << 4);
    }
  }
#pragma unroll
  for (int nf = 0; nf < 4; nf++) {
    int row = wn * 64 + nf * 16 + r0;
#pragma unroll
    for (int ks = 0; ks < 2; ks++) {
      int c = ks * 4 + kcb;
      boff[nf][ks] = row * 128 + ((c ^ (row & 7)) << 4);
    }
  }

  const int NT = H_DIM / 64;   // 16
  // prologue: stage kt=0 into buf0 (8 loads outstanding)
  GLA(0, 0, 0); GLA(1, 0, 0); GLA(2, 0, 0); GLA(3, 0, 0);
  GLG(0, 0, 0); GLG(1, 0, 0); GLU(0, 0, 0); GLU(1, 0, 0);

  bf16x8 a0[2][2], a1[2][2], bb[4][2];

  for (int kt = 0; kt < NT; kt++) {
    int buf = kt & 1, nbuf = buf ^ 1;
    int ktn = (kt + 1 < NT) ? kt + 1 : 0;
    const char* Ab = (const char*)Alds[buf];
    const char* Bgb = (const char*)Bglds[buf];
    const char* Bub = (const char*)Bulds[buf];

    // all waves done reading nbuf (prev iter) -> safe to overwrite
    __builtin_amdgcn_s_barrier();
    // issue all 8 stage loads for kt+1 -> nbuf
    GLA(0, ktn, nbuf); GLA(1, ktn, nbuf); GLA(2, ktn, nbuf); GLA(3, ktn, nbuf);
    GLG(0, ktn, nbuf); GLG(1, ktn, nbuf); GLU(0, ktn, nbuf); GLU(1, ktn, nbuf);
    // drain last iter's 8 loads (full K-tile of distance); keep new 8 in flight
    asm volatile("s_waitcnt vmcnt(8)" ::: "memory");
    __builtin_amdgcn_s_barrier();   // collective: buf fully staged

    // ---- P1: read a0 + bg; mfma g m0/m1 ----
#pragma unroll
    for (int mf = 0; mf < 2; mf++)
#pragma unroll
      for (int ks = 0; ks < 2; ks++)
        a0[mf][ks] = *(const bf16x8*)(Ab + aoff[mf][ks]);
#pragma unroll
    for (int nf = 0; nf < 4; nf++)
#pragma unroll
      for (int ks = 0; ks < 2; ks++)
        bb[nf][ks] = *(const bf16x8*)(Bgb + boff[nf][ks]);
    asm volatile("s_waitcnt lgkmcnt(0)" ::: "memory");
    __builtin_amdgcn_sched_barrier(0);
    __builtin_amdgcn_s_setprio(1);
#pragma unroll
    for (int mf = 0; mf < 2; mf++)
#pragma unroll
      for (int nf = 0; nf < 4; nf++)
#pragma unroll
        for (int ks = 0; ks < 2; ks++)
          accg[mf][nf] = __builtin_amdgcn_mfma_f32_16x16x32_bf16(
              a0[mf][ks], bb[nf][ks], accg[mf][nf], 0, 0, 0);
    __builtin_amdgcn_s_setprio(0);

    // ---- P2: read a1; mfma g m2/m3 ----
#pragma unroll
    for (int mf = 0; mf < 2; mf++)
#pragma unroll
      for (int ks = 0; ks < 2; ks++)
        a1[mf][ks] = *(const bf16x8*)(Ab + aoff[2 + mf][ks]);
    asm volatile("s_waitcnt lgkmcnt(0)" ::: "memory");
    __builtin_amdgcn_sched_barrier(0);
    __builtin_amdgcn_s_setprio(1);
#pragma unroll
    for (int mf = 0; mf < 2; mf++)
#pragma unroll
      for (int nf = 0; nf < 4; nf++)
#pragma unroll
        for (int ks = 0; ks < 2; ks++)
          accg[2 + mf][nf] = __builtin_amdgcn_mfma_f32_16x16x32_bf16(
              a1[mf][ks], bb[nf][ks], accg[2 + mf][nf], 0, 0, 0);
    __builtin_amdgcn_s_setprio(0);

    // ---- P3: read bu (overwrite bb); mfma u m0/m1 ----
#pragma unroll
    for (int nf = 0; nf < 4; nf++)
#pragma unroll
      for (int ks = 0; ks < 2; ks++)
        bb[nf][ks] = *(const bf16x8*)(Bub + boff[nf][ks]);
    asm volatile("s_waitcnt lgkmcnt(0)" ::: "memory");
    __builtin_amdgcn_sched_barrier(0);
    __builtin_amdgcn_s_setprio(1);
#pragma unroll
    for (int mf = 0; mf < 2; mf++)
#pragma unroll
      for (int nf = 0; nf < 4; nf++)
#pragma unroll
        for (int ks = 0; ks < 2; ks++)
          accu[mf][nf] = __builtin_amdgcn_mfma_f32_16x16x32_bf16(
              a0[mf][ks], bb[nf][ks], accu[mf][nf], 0, 0, 0);
    __builtin_amdgcn_s_setprio(0);

    // ---- P4: mfma u m2/m3 ----
    __builtin_amdgcn_s_setprio(1);
#pragma unroll
    for (int mf = 0; mf < 2; mf++)
#pragma unroll
      for (int nf = 0; nf < 4; nf++)
#pragma unroll
        for (int ks = 0; ks < 2; ks++)
          accu[2 + mf][nf] = __builtin_amdgcn_mfma_f32_16x16x32_bf16(
              a1[mf][ks], bb[nf][ks], accu[2 + mf][nf], 0, 0, 0);
    __builtin_amdgcn_s_setprio(0);
  }
  asm volatile("s_waitcnt vmcnt(0)" ::: "memory");
#undef GLA
#undef GLG
#undef GLU

  int rowBase = segStart + mtile * 256 + wm * 64;
#pragma unroll
  for (int mf = 0; mf < 4; mf++)
#pragma unroll
    for (int nf = 0; nf < 4; nf++) {
      int col = nt * 128 + wn * 64 + nf * 16 + r0;
#pragma unroll
      for (int j = 0; j < 4; j++) {
        int r = rowBase + mf * 16 + (lane >> 4) * 4 + j;
        if (r < segEnd) {
          float g = accg[mf][nf][j];
          float u = accu[mf][nf][j];
          float h = (g / (1.f + __expf(-g))) * u;
          Hb[(size_t)r * IE_DIM + col] = f2bf(h);
        }
      }
    }
}

// ---------------- GEMM2 (R7 proven): out[tok] = h Wd, fp32 scatter ----------------
// BM=128, BN=128, BK=32. 8 waves 64x32. 3-buffer depth-2, vmcnt(2).
__global__ __launch_bounds__(512) void k_gemm2(
    const unsigned short* __restrict__ Hb,
    const unsigned short* __restrict__ WdT,
    float* __restrict__ out,
    const int* __restrict__ offsets, const int* __restrict__ tileOff,
    const int* __restrict__ tokofrow) {
  // bijective XCD swizzle for nwg=1080: q=135, r=0
  int bid0 = blockIdx.x;
  int wg = (bid0 & 7) * 135 + (bid0 >> 3);
  int nt = wg & 7;
  int mlin = wg >> 3;
  if (mlin >= tileOff[E_NUM]) return;
  int e = 0;
#pragma unroll
  for (int i = 1; i < E_NUM; i++)
    if (mlin >= tileOff[i]) e = i;
  int mtile = mlin - tileOff[e];
  int segStart = offsets[e], segEnd = offsets[e + 1];
  int M = segEnd - segStart;

  __shared__ unsigned short Alds[3][128 * 32];
  __shared__ unsigned short Blds[3][128 * 32];

  int tid = threadIdx.x;
  int lane = tid & 63;
  int w = tid >> 6;
  int wm = w >> 2;
  int wn = w & 3;

  f32x4 acc[4][2];
#pragma unroll
  for (int i = 0; i < 4; i++)
#pragma unroll
    for (int j = 0; j < 2; j++) acc[i][j] = (f32x4)(0.f);

  int sr = tid >> 2;
  int sc = tid & 3;
  int scc = sc ^ ((sr >> 1) & 3);
  int grow = mtile * 128 + sr;
  if (grow > M - 1) grow = M - 1;
  const unsigned short* Arow = Hb + (size_t)(segStart + grow) * IE_DIM + scc * 8;
  const unsigned short* Brow =
      WdT + (size_t)e * H_DIM * IE_DIM + (size_t)(nt * 128 + sr) * IE_DIM + scc * 8;

#define STAGE2(buf, k0)                                            \
  {                                                                \
    gload16(Arow + (k0), (char*)Alds[buf] + tid * 16);             \
    gload16(Brow + (k0), (char*)Blds[buf] + tid * 16);             \
  }

  int kc = lane >> 4;
  int arow[4], browv[2];
#pragma unroll
  for (int mf = 0; mf < 4; mf++) arow[mf] = wm * 64 + mf * 16 + (lane & 15);
#pragma unroll
  for (int nf = 0; nf < 2; nf++) browv[nf] = wn * 32 + nf * 16 + (lane & 15);

  const int NT = IE_DIM / 32;
  STAGE2(0, 0);
  STAGE2(1, 32);

  int cur = 0;
  for (int t = 0; t < NT; t++) {
    asm volatile("s_waitcnt vmcnt(2)" ::: "memory");
    __builtin_amdgcn_s_barrier();
    __builtin_amdgcn_sched_barrier(0);
    int tn = t + 2; if (tn >= NT) tn -= NT;
    int nbuf = cur + 2; if (nbuf >= 3) nbuf -= 3;
    STAGE2(nbuf, tn * 32);

    bf16x8 a[4], b[2];
#pragma unroll
    for (int mf = 0; mf < 4; mf++) {
      int row = arow[mf];
      int byte = row * 64 + ((kc ^ ((row >> 1) & 3)) << 4);
      a[mf] = *(const bf16x8*)((const char*)Alds[cur] + byte);
    }
#pragma unroll
    for (int nf = 0; nf < 2; nf++) {
      int row = browv[nf];
      int byte = row * 64 + ((kc ^ ((row >> 1) & 3)) << 4);
      b[nf] = *(const bf16x8*)((const char*)Blds[cur] + byte);
    }
    __builtin_amdgcn_s_setprio(1);
#pragma unroll
    for (int mf = 0; mf < 4; mf++)
#pragma unroll
      for (int nf = 0; nf < 2; nf++)
        acc[mf][nf] = __builtin_amdgcn_mfma_f32_16x16x32_bf16(
            a[mf], b[nf], acc[mf][nf], 0, 0, 0);
    __builtin_amdgcn_s_setprio(0);
    cur = (cur + 1 == 3) ? 0 : cur + 1;
  }
#undef STAGE2
  asm volatile("s_waitcnt vmcnt(0)" ::: "memory");

  int rowBase = segStart + mtile * 128 + wm * 64;
#pragma unroll
  for (int mf = 0; mf < 4; mf++)
#pragma unroll
    for (int nf = 0; nf < 2; nf++) {
      int col = nt * 128 + wn * 32 + nf * 16 + (lane & 15);
#pragma unroll
      for (int j = 0; j < 4; j++) {
        int r = rowBase + mf * 16 + (lane >> 4) * 4 + j;
        if (r < segEnd) {
          int t = tokofrow[r];
          out[(size_t)t * H_DIM + col] = acc[mf][nf][j];
        }
      }
    }
}

// ---------------- workspace layout (bytes) ----------------
#define WS_XS    ((size_t)0)             // 32MB
#define WS_WGT   ((size_t)33554432)      // 8MB
#define WS_WUT   ((size_t)41943040)      // 8MB
#define WS_WDT   ((size_t)50331648)      // 8MB
#define WS_HB    ((size_t)58720256)      // 16MB
#define WS_EID   ((size_t)75497472)      // 64KB
#define WS_TOK   ((size_t)75563008)      // 64KB
#define WS_OFF   ((size_t)75628544)      // offsets/tileOffs (1KB)
#define WS_BC    ((size_t)75629568)      // blockCnt 32KB
#define WS_BB    ((size_t)75662336)      // blockBase 32KB

extern "C" void kernel_launch(void* const* d_in, const int* in_sizes, int n_in,
                              void* d_out, int out_size, void* d_ws, size_t ws_size,
                              hipStream_t stream) {
  const float* hs  = (const float*)d_in[0];
  const int*   tok = (const int*)d_in[1];
  const float* mu  = (const float*)d_in[2];
  const float* wg  = (const float*)d_in[3];
  const float* wu  = (const float*)d_in[4];
  const float* wd  = (const float*)d_in[5];
  const float* mrw = (const float*)d_in[6];
  float* out = (float*)d_out;
  char* ws = (char*)d_ws;

  unsigned short* Xs  = (unsigned short*)(ws + WS_XS);
  unsigned short* WgT = (unsigned short*)(ws + WS_WGT);
  unsigned short* WuT = (unsigned short*)(ws + WS_WUT);
  unsigned short* WdT = (unsigned short*)(ws + WS_WDT);
  unsigned short* Hb  = (unsigned short*)(ws + WS_HB);
  int* eid      = (int*)(ws + WS_EID);
  int* tokofrow = (int*)(ws + WS_TOK);
  int* offsets   = (int*)(ws + WS_OFF);  // [9]
  int* tileOff   = offsets + 16;         // [9]  256-gran (gemm1)
  int* tileOff128= offsets + 32;         // [9]  128-gran (gemm2)
  int* blockCnt = (int*)(ws + WS_BC);    // [1024][8]
  int* blockBase= (int*)(ws + WS_BB);    // [1024][8]

  k_pre<<<4096, 256, 0, stream>>>(mu, tok, mrw, eid, blockCnt,
                                  wg, wu, wd, WgT, WuT, WdT);
  k_scan2<<<1, 1024, 0, stream>>>(blockCnt, blockBase, offsets, tileOff, tileOff128);
  k_gather<<<1024, 256, 0, stream>>>(hs, eid, blockBase, tokofrow, Xs);
  // gemm1: worst-case M-tiles(256) = 71; x4 n-tiles = 284
  k_gemm1<<<284, 512, 0, stream>>>(Xs, WgT, WuT, Hb, offsets, tileOff);
  // gemm2: worst-case M-tiles(128) = 135; x8 n-tiles = 1080
  k_gemm2<<<135 * 8, 512, 0, stream>>>(Hb, WdT, out, offsets, tileOff128, tokofrow);
}

// Round 13
// 166.989 us; speedup vs baseline: 1.6530x; 1.0121x over previous
//
#include <hip/hip_runtime.h>
#include <stdint.h>

// Problem constants
#define T_TOK   16384      // B*S
#define H_DIM   1024
#define IE_DIM  512
#define E_NUM   8
#define V_MAX   100000

typedef __attribute__((ext_vector_type(8))) short bf16x8;
typedef __attribute__((ext_vector_type(4))) float f32x4;
typedef unsigned long long ull;

__device__ __forceinline__ unsigned short f2bf(float f) {
  union { float f; unsigned u; } v; v.f = f;
  unsigned r = v.u + 0x7fffu + ((v.u >> 16) & 1u);
  return (unsigned short)(r >> 16);
}

__device__ __forceinline__ void gload16(const void* g, void* l) {
  __builtin_amdgcn_global_load_lds(
      (const __attribute__((address_space(1))) unsigned int*)g,
      (__attribute__((address_space(3))) unsigned int*)(unsigned int)(uintptr_t)l,
      16, 0, 0);
}

// ---------------- fused pre-pass: route (blocks 0..1023) + weight transpose (1024..4095) ----------------
__global__ __launch_bounds__(256) void k_pre(
    const float* __restrict__ mu, const int* __restrict__ tok,
    const float* __restrict__ mrw, int* __restrict__ eid,
    int* __restrict__ blockCnt,
    const float* __restrict__ wg, const float* __restrict__ wu,
    const float* __restrict__ wd, unsigned short* __restrict__ WgT,
    unsigned short* __restrict__ WuT, unsigned short* __restrict__ WdT) {
  __shared__ unsigned short lds[64][72];
  int tid = threadIdx.x;

  if (blockIdx.x < 1024) {
    int* cnt = (int*)&lds[0][0];
    if (tid < 8) cnt[tid] = 0;
    int wv = blockIdx.x * 4 + (tid >> 6);
    int t0 = wv * 4;
    int lane = tid & 63;
    const float4* mrw4 = (const float4*)mrw;

    float acc[4][E_NUM];
#pragma unroll
    for (int i = 0; i < 4; i++)
#pragma unroll
      for (int e = 0; e < E_NUM; e++) acc[i][e] = 0.f;

#pragma unroll
    for (int j = 0; j < 4; j++) {
      int idx = lane + 64 * j;
      float4 wr[E_NUM];
#pragma unroll
      for (int e = 0; e < E_NUM; e++) wr[e] = mrw4[e * 256 + idx];
#pragma unroll
      for (int i = 0; i < 4; i++) {
        float4 m = ((const float4*)(mu + (size_t)(t0 + i) * H_DIM))[idx];
#pragma unroll
        for (int e = 0; e < E_NUM; e++)
          acc[i][e] += m.x * wr[e].x + m.y * wr[e].y + m.z * wr[e].z + m.w * wr[e].w;
      }
    }
#pragma unroll
    for (int i = 0; i < 4; i++)
#pragma unroll
      for (int e = 0; e < E_NUM; e++)
#pragma unroll
        for (int off = 32; off >= 1; off >>= 1)
          acc[i][e] += __shfl_xor(acc[i][e], off, 64);

    __syncthreads();
#pragma unroll
    for (int i = 0; i < 4; i++) {
      int tv = tok[t0 + i];
      if (tv < 0) tv = 0;
      if (tv > V_MAX - 1) tv = V_MAX - 1;
      int base = tv & 7;
      int best = 0; float bs = -1e30f;
#pragma unroll
      for (int e = 0; e < E_NUM; e++) {
        float s = acc[i][e] + (e == base ? 10.f : 0.f);
        if (s > bs) { bs = s; best = e; }
      }
      if (lane == i) {
        eid[t0 + i] = best;
        atomicAdd(&cnt[best], 1);
      }
    }
    __syncthreads();
    if (tid < 8) blockCnt[blockIdx.x * 8 + tid] = cnt[tid];
  } else {
    int sel = (blockIdx.x - 1024) >> 10;
    int blk = blockIdx.x & 1023;
    const float* src; unsigned short* dst; int R, C;
    if (sel == 0)      { src = wg; dst = WgT; R = H_DIM; C = IE_DIM; }
    else if (sel == 1) { src = wu; dst = WuT; R = H_DIM; C = IE_DIM; }
    else               { src = wd; dst = WdT; R = IE_DIM; C = H_DIM; }
    int tpe = (R >> 6) * (C >> 6);
    int e = blk / tpe;
    int rem = blk % tpe;
    int tr = rem / (C >> 6);
    int tc = rem % (C >> 6);
    const float* s = src + (size_t)e * R * C;
    unsigned short* d = dst + (size_t)e * R * C;
    int r0 = tid >> 4;
    int c0 = (tid & 15) * 4;
#pragma unroll
    for (int i = 0; i < 4; i++) {
      int r = r0 + i * 16;
      float4 v = *(const float4*)(s + (size_t)(tr * 64 + r) * C + tc * 64 + c0);
      lds[r][c0 + 0] = f2bf(v.x); lds[r][c0 + 1] = f2bf(v.y);
      lds[r][c0 + 2] = f2bf(v.z); lds[r][c0 + 3] = f2bf(v.w);
    }
    __syncthreads();
    int oc = tid >> 2;
    int ob = (tid & 3) * 16;
    unsigned short tmp[16];
#pragma unroll
    for (int i = 0; i < 16; i++) tmp[i] = lds[ob + i][oc];
    uint4* dp = (uint4*)(d + (size_t)(tc * 64 + oc) * R + tr * 64 + ob);
    dp[0] = ((uint4*)tmp)[0];
    dp[1] = ((uint4*)tmp)[1];
  }
}

// ---------------- scan: packed 8x16-bit Hillis-Steele over 1024 blocks ----------------
__global__ __launch_bounds__(1024) void k_scan2(
    const int* __restrict__ blockCnt, int* __restrict__ blockBase,
    int* __restrict__ offsets, int* __restrict__ tileOff,
    int* __restrict__ tileOff128) {
  int b = threadIdx.x;
  __shared__ ull s0[1024], s1[1024];
  __shared__ int offL[8];
  const int4* p = (const int4*)(blockCnt + b * 8);
  int4 x0 = p[0], x1 = p[1];
  int c[8] = {x0.x, x0.y, x0.z, x0.w, x1.x, x1.y, x1.z, x1.w};
  ull v0 = (ull)c[0] | ((ull)c[1] << 16) | ((ull)c[2] << 32) | ((ull)c[3] << 48);
  ull v1 = (ull)c[4] | ((ull)c[5] << 16) | ((ull)c[6] << 32) | ((ull)c[7] << 48);
  s0[b] = v0; s1[b] = v1;
  __syncthreads();
  for (int st = 1; st < 1024; st <<= 1) {
    ull a0 = 0, a1 = 0;
    if (b >= st) { a0 = s0[b - st]; a1 = s1[b - st]; }
    __syncthreads();
    v0 += a0; v1 += a1;
    s0[b] = v0; s1[b] = v1;
    __syncthreads();
  }
  if (b == 1023) {
    int tot[8];
#pragma unroll
    for (int e = 0; e < 4; e++) tot[e] = (int)((v0 >> (16 * e)) & 0xFFFF);
#pragma unroll
    for (int e = 0; e < 4; e++) tot[4 + e] = (int)((v1 >> (16 * e)) & 0xFFFF);
    int s = 0, ts = 0, ts2 = 0;
    for (int e = 0; e < E_NUM; e++) {
      offsets[e] = s; offL[e] = s;
      tileOff[e] = ts; tileOff128[e] = ts2;
      s += tot[e];
      ts += (tot[e] + 255) >> 8;     // 256-row M-tiles (gemm1)
      ts2 += (tot[e] + 127) >> 7;    // 128-row M-tiles (gemm2)
    }
    offsets[E_NUM] = s; tileOff[E_NUM] = ts; tileOff128[E_NUM] = ts2;
  }
  __syncthreads();
  int be[8];
#pragma unroll
  for (int e = 0; e < 4; e++)
    be[e] = offL[e] + (int)((v0 >> (16 * e)) & 0xFFFF) - c[e];
#pragma unroll
  for (int e = 0; e < 4; e++)
    be[4 + e] = offL[4 + e] + (int)((v1 >> (16 * e)) & 0xFFFF) - c[4 + e];
  int4* q = (int4*)(blockBase + b * 8);
  q[0] = make_int4(be[0], be[1], be[2], be[3]);
  q[1] = make_int4(be[4], be[5], be[6], be[7]);
}

// ---------------- gather: deterministic rank, no atomics ----------------
__global__ __launch_bounds__(256) void k_gather(
    const float* __restrict__ hs, const int* __restrict__ eid,
    const int* __restrict__ blockBase, int* __restrict__ tokofrow,
    unsigned short* __restrict__ Xs) {
  int b = blockIdx.x;
  int tid = threadIdx.x;
  __shared__ int eL[16];
  __shared__ int posL[16];
  if (tid < 16) eL[tid] = eid[b * 16 + tid];
  __syncthreads();
  if (tid < 16) {
    int e = eL[tid];
    int r = 0;
    for (int j = 0; j < tid; j++) r += (eL[j] == e);
    int pos = blockBase[b * 8 + e] + r;
    posL[tid] = pos;
    tokofrow[pos] = b * 16 + tid;
  }
  __syncthreads();
  int w = tid >> 6, lane = tid & 63;
#pragma unroll
  for (int i = 0; i < 4; i++) {
    int li = w * 4 + i;
    int t = b * 16 + li;
    int pos = posL[li];
    const float4* src = (const float4*)(hs + (size_t)t * H_DIM);
    unsigned short* drow = Xs + (size_t)pos * H_DIM;
#pragma unroll
    for (int j = 0; j < 4; j++) {
      float4 v = src[lane + 64 * j];
      ushort4 bb;
      bb.x = f2bf(v.x); bb.y = f2bf(v.y); bb.z = f2bf(v.z); bb.w = f2bf(v.w);
      *(ushort4*)(drow + (lane + 64 * j) * 4) = bb;
    }
  }
}

// ---------------- GEMM1 (m201-faithful 8-phase): h = silu(X Wg) * (X Wu) ----------------
// BM=256, BN=128(dual g+u), half-K=32 granularity, 4 half-buffers (128KB).
// 8 waves 4Mx2N. Per half: 4 phases {ds_reads; 1 stage; barrier; lgkm0; 8 MFMA; barrier}.
// Prefetch distance 3 halves; single vmcnt(8) per half at P4.
__global__ __launch_bounds__(512, 1) void k_gemm1(
    const unsigned short* __restrict__ Xs,
    const unsigned short* __restrict__ WgT,
    const unsigned short* __restrict__ WuT,
    unsigned short* __restrict__ Hb,
    const int* __restrict__ offsets, const int* __restrict__ tileOff) {
  // bijective XCD swizzle for nwg=284: q=35, r=4
  int bid0 = blockIdx.x;
  int xcd = bid0 & 7, seq = bid0 >> 3;
  int wg = (xcd < 4 ? xcd * 36 : 144 + (xcd - 4) * 35) + seq;
  int nt = wg & 3;          // 4 n-tiles of 128
  int mlin = wg >> 2;
  if (mlin >= tileOff[E_NUM]) return;
  int e = 0;
#pragma unroll
  for (int i = 1; i < E_NUM; i++)
    if (mlin >= tileOff[i]) e = i;
  int mtile = mlin - tileOff[e];
  int segStart = offsets[e], segEnd = offsets[e + 1];
  int M = segEnd - segStart;

  __shared__ unsigned short Alds[4][256 * 32];   // 4 x 16KB
  __shared__ unsigned short Bglds[4][128 * 32];  // 4 x 8KB
  __shared__ unsigned short Bulds[4][128 * 32];  // 4 x 8KB

  int tid = threadIdx.x;
  int lane = tid & 63;
  int w = tid >> 6;
  int wm = w >> 1;        // 0..3
  int wn = w & 1;         // 0..1
  int r0 = lane & 15;
  int kcb = lane >> 4;    // 0..3 (8 bf16 each -> K=32)

  f32x4 accg[4][4], accu[4][4];
#pragma unroll
  for (int i = 0; i < 4; i++)
#pragma unroll
    for (int j = 0; j < 4; j++) {
      accg[i][j] = (f32x4)(0.f);
      accu[i][j] = (f32x4)(0.f);
    }

  // ---- staging sources (per thread, K-col added per half) ----
  int arow0 = tid >> 2;           // 0..127
  int arow1 = arow0 + 128;        // 128..255
  int acs = (tid & 3) ^ ((arow0 >> 1) & 3);   // same for arow1 (128/2 % 4 == 0)
  int ga0 = mtile * 256 + arow0; if (ga0 > M - 1) ga0 = M - 1;
  int ga1 = mtile * 256 + arow1; if (ga1 > M - 1) ga1 = M - 1;
  const unsigned short* Aad0 = Xs + (size_t)(segStart + ga0) * H_DIM + acs * 8;
  const unsigned short* Aad1 = Xs + (size_t)(segStart + ga1) * H_DIM + acs * 8;
  int brow = tid >> 2;            // 0..127
  int bcs = (tid & 3) ^ ((brow >> 1) & 3);
  const unsigned short* Bgad =
      WgT + (size_t)e * IE_DIM * H_DIM + (size_t)(nt * 128 + brow) * H_DIM + bcs * 8;
  const unsigned short* Buad =
      WuT + (size_t)e * IE_DIM * H_DIM + (size_t)(nt * 128 + brow) * H_DIM + bcs * 8;

#define SGA0(h) gload16(Aad0 + ((h) & 31) * 32, (char*)Alds + ((h) & 3) * 16384 + tid * 16)
#define SGA1(h) gload16(Aad1 + ((h) & 31) * 32, (char*)Alds + ((h) & 3) * 16384 + 8192 + tid * 16)
#define SGG(h)  gload16(Bgad + ((h) & 31) * 32, (char*)Bglds + ((h) & 3) * 8192 + tid * 16)
#define SGU(h)  gload16(Buad + ((h) & 31) * 32, (char*)Bulds + ((h) & 3) * 8192 + tid * 16)

  // ---- fragment read offsets within a half-buffer (row stride 64B) ----
  int aoff[4], boff[4];
#pragma unroll
  for (int mf = 0; mf < 4; mf++) {
    int row = wm * 64 + mf * 16 + r0;
    aoff[mf] = row * 64 + ((kcb ^ ((row >> 1) & 3)) << 4);
  }
#pragma unroll
  for (int nf = 0; nf < 4; nf++) {
    int row = wn * 64 + nf * 16 + r0;
    boff[nf] = row * 64 + ((kcb ^ ((row >> 1) & 3)) << 4);
  }

  // ---- prologue: stage halves 0,1,2 (12 loads/thread) ----
  SGA0(0); SGA1(0); SGG(0); SGU(0);
  SGA0(1); SGA1(1); SGG(1); SGU(1);
  SGA0(2); SGA1(2); SGG(2); SGU(2);
  asm volatile("s_waitcnt vmcnt(8)" ::: "memory");   // half 0 landed
  __builtin_amdgcn_s_barrier();

  const int NH = H_DIM / 32;   // 32 halves
  for (int hh = 0; hh < NH; hh += 4) {
#pragma unroll
    for (int u = 0; u < 4; u++) {
      int h = hh + u;
      const char* Ab  = (const char*)Alds + u * 16384;
      const char* Bgb = (const char*)Bglds + u * 8192;
      const char* Bub = (const char*)Bulds + u * 8192;
      int hn = h + 3;
      bf16x8 a[4], bg[4], bu[4];

      // ---- P1: read a0,a1 + bg; stage SGA0(hn); 8 MFMA g m01 ----
      a[0] = *(const bf16x8*)(Ab + aoff[0]);
      a[1] = *(const bf16x8*)(Ab + aoff[1]);
#pragma unroll
      for (int nf = 0; nf < 4; nf++) bg[nf] = *(const bf16x8*)(Bgb + boff[nf]);
      SGA0(hn);
      __builtin_amdgcn_s_barrier();
      asm volatile("s_waitcnt lgkmcnt(0)" ::: "memory");
      __builtin_amdgcn_sched_barrier(0);
      __builtin_amdgcn_s_setprio(1);
#pragma unroll
      for (int mf = 0; mf < 2; mf++)
#pragma unroll
        for (int nf = 0; nf < 4; nf++)
          accg[mf][nf] = __builtin_amdgcn_mfma_f32_16x16x32_bf16(
              a[mf], bg[nf], accg[mf][nf], 0, 0, 0);
      __builtin_amdgcn_s_setprio(0);
      __builtin_amdgcn_s_barrier();

      // ---- P2: read a2,a3; stage SGA1(hn); 8 MFMA g m23 ----
      a[2] = *(const bf16x8*)(Ab + aoff[2]);
      a[3] = *(const bf16x8*)(Ab + aoff[3]);
      SGA1(hn);
      __builtin_amdgcn_s_barrier();
      asm volatile("s_waitcnt lgkmcnt(0)" ::: "memory");
      __builtin_amdgcn_sched_barrier(0);
      __builtin_amdgcn_s_setprio(1);
#pragma unroll
      for (int mf = 0; mf < 2; mf++)
#pragma unroll
        for (int nf = 0; nf < 4; nf++)
          accg[2 + mf][nf] = __builtin_amdgcn_mfma_f32_16x16x32_bf16(
              a[2 + mf], bg[nf], accg[2 + mf][nf], 0, 0, 0);
      __builtin_amdgcn_s_setprio(0);
      __builtin_amdgcn_s_barrier();

      // ---- P3: read bu; stage SGG(hn); 8 MFMA u m01 ----
#pragma unroll
      for (int nf = 0; nf < 4; nf++) bu[nf] = *(const bf16x8*)(Bub + boff[nf]);
      SGG(hn);
      __builtin_amdgcn_s_barrier();
      asm volatile("s_waitcnt lgkmcnt(0)" ::: "memory");
      __builtin_amdgcn_sched_barrier(0);
      __builtin_amdgcn_s_setprio(1);
#pragma unroll
      for (int mf = 0; mf < 2; mf++)
#pragma unroll
        for (int nf = 0; nf < 4; nf++)
          accu[mf][nf] = __builtin_amdgcn_mfma_f32_16x16x32_bf16(
              a[mf], bu[nf], accu[mf][nf], 0, 0, 0);
      __builtin_amdgcn_s_setprio(0);
      __builtin_amdgcn_s_barrier();

      // ---- P4: stage SGU(hn); vmcnt(8); 8 MFMA u m23 ----
      SGU(hn);
      asm volatile("s_waitcnt vmcnt(8)" ::: "memory");  // drain half h+1
      __builtin_amdgcn_s_barrier();
      __builtin_amdgcn_s_setprio(1);
#pragma unroll
      for (int mf = 0; mf < 2; mf++)
#pragma unroll
        for (int nf = 0; nf < 4; nf++)
          accu[2 + mf][nf] = __builtin_amdgcn_mfma_f32_16x16x32_bf16(
              a[2 + mf], bu[nf], accu[2 + mf][nf], 0, 0, 0);
      __builtin_amdgcn_s_setprio(0);
      __builtin_amdgcn_s_barrier();
    }
  }
  asm volatile("s_waitcnt vmcnt(0)" ::: "memory");
#undef SGA0
#undef SGA1
#undef SGG
#undef SGU

  int rowBase = segStart + mtile * 256 + wm * 64;
#pragma unroll
  for (int mf = 0; mf < 4; mf++)
#pragma unroll
    for (int nf = 0; nf < 4; nf++) {
      int col = nt * 128 + wn * 64 + nf * 16 + r0;
#pragma unroll
      for (int j = 0; j < 4; j++) {
        int r = rowBase + mf * 16 + (lane >> 4) * 4 + j;
        if (r < segEnd) {
          float g = accg[mf][nf][j];
          float u = accu[mf][nf][j];
          float h = (g / (1.f + __expf(-g))) * u;
          Hb[(size_t)r * IE_DIM + col] = f2bf(h);
        }
      }
    }
}

// ---------------- GEMM2 (R7 proven): out[tok] = h Wd, fp32 scatter ----------------
__global__ __launch_bounds__(512) void k_gemm2(
    const unsigned short* __restrict__ Hb,
    const unsigned short* __restrict__ WdT,
    float* __restrict__ out,
    const int* __restrict__ offsets, const int* __restrict__ tileOff,
    const int* __restrict__ tokofrow) {
  // bijective XCD swizzle for nwg=1080: q=135, r=0
  int bid0 = blockIdx.x;
  int wg = (bid0 & 7) * 135 + (bid0 >> 3);
  int nt = wg & 7;
  int mlin = wg >> 3;
  if (mlin >= tileOff[E_NUM]) return;
  int e = 0;
#pragma unroll
  for (int i = 1; i < E_NUM; i++)
    if (mlin >= tileOff[i]) e = i;
  int mtile = mlin - tileOff[e];
  int segStart = offsets[e], segEnd = offsets[e + 1];
  int M = segEnd - segStart;

  __shared__ unsigned short Alds[3][128 * 32];
  __shared__ unsigned short Blds[3][128 * 32];

  int tid = threadIdx.x;
  int lane = tid & 63;
  int w = tid >> 6;
  int wm = w >> 2;
  int wn = w & 3;

  f32x4 acc[4][2];
#pragma unroll
  for (int i = 0; i < 4; i++)
#pragma unroll
    for (int j = 0; j < 2; j++) acc[i][j] = (f32x4)(0.f);

  int sr = tid >> 2;
  int sc = tid & 3;
  int scc = sc ^ ((sr >> 1) & 3);
  int grow = mtile * 128 + sr;
  if (grow > M - 1) grow = M - 1;
  const unsigned short* Arow = Hb + (size_t)(segStart + grow) * IE_DIM + scc * 8;
  const unsigned short* Brow =
      WdT + (size_t)e * H_DIM * IE_DIM + (size_t)(nt * 128 + sr) * IE_DIM + scc * 8;

#define STAGE2(buf, k0)                                            \
  {                                                                \
    gload16(Arow + (k0), (char*)Alds[buf] + tid * 16);             \
    gload16(Brow + (k0), (char*)Blds[buf] + tid * 16);             \
  }

  int kc = lane >> 4;
  int arow[4], browv[2];
#pragma unroll
  for (int mf = 0; mf < 4; mf++) arow[mf] = wm * 64 + mf * 16 + (lane & 15);
#pragma unroll
  for (int nf = 0; nf < 2; nf++) browv[nf] = wn * 32 + nf * 16 + (lane & 15);

  const int NT = IE_DIM / 32;
  STAGE2(0, 0);
  STAGE2(1, 32);

  int cur = 0;
  for (int t = 0; t < NT; t++) {
    asm volatile("s_waitcnt vmcnt(2)" ::: "memory");
    __builtin_amdgcn_s_barrier();
    __builtin_amdgcn_sched_barrier(0);
    int tn = t + 2; if (tn >= NT) tn -= NT;
    int nbuf = cur + 2; if (nbuf >= 3) nbuf -= 3;
    STAGE2(nbuf, tn * 32);

    bf16x8 a[4], b[2];
#pragma unroll
    for (int mf = 0; mf < 4; mf++) {
      int row = arow[mf];
      int byte = row * 64 + ((kc ^ ((row >> 1) & 3)) << 4);
      a[mf] = *(const bf16x8*)((const char*)Alds[cur] + byte);
    }
#pragma unroll
    for (int nf = 0; nf < 2; nf++) {
      int row = browv[nf];
      int byte = row * 64 + ((kc ^ ((row >> 1) & 3)) << 4);
      b[nf] = *(const bf16x8*)((const char*)Blds[cur] + byte);
    }
    __builtin_amdgcn_s_setprio(1);
#pragma unroll
    for (int mf = 0; mf < 4; mf++)
#pragma unroll
      for (int nf = 0; nf < 2; nf++)
        acc[mf][nf] = __builtin_amdgcn_mfma_f32_16x16x32_bf16(
            a[mf], b[nf], acc[mf][nf], 0, 0, 0);
    __builtin_amdgcn_s_setprio(0);
    cur = (cur + 1 == 3) ? 0 : cur + 1;
  }
#undef STAGE2
  asm volatile("s_waitcnt vmcnt(0)" ::: "memory");

  int rowBase = segStart + mtile * 128 + wm * 64;
#pragma unroll
  for (int mf = 0; mf < 4; mf++)
#pragma unroll
    for (int nf = 0; nf < 2; nf++) {
      int col = nt * 128 + wn * 32 + nf * 16 + (lane & 15);
#pragma unroll
      for (int j = 0; j < 4; j++) {
        int r = rowBase + mf * 16 + (lane >> 4) * 4 + j;
        if (r < segEnd) {
          int t = tokofrow[r];
          out[(size_t)t * H_DIM + col] = acc[mf][nf][j];
        }
      }
    }
}

// ---------------- workspace layout (bytes) ----------------
#define WS_XS    ((size_t)0)             // 32MB
#define WS_WGT   ((size_t)33554432)      // 8MB
#define WS_WUT   ((size_t)41943040)      // 8MB
#define WS_WDT   ((size_t)50331648)      // 8MB
#define WS_HB    ((size_t)58720256)      // 16MB
#define WS_EID   ((size_t)75497472)      // 64KB
#define WS_TOK   ((size_t)75563008)      // 64KB
#define WS_OFF   ((size_t)75628544)      // offsets/tileOffs (1KB)
#define WS_BC    ((size_t)75629568)      // blockCnt 32KB
#define WS_BB    ((size_t)75662336)      // blockBase 32KB

extern "C" void kernel_launch(void* const* d_in, const int* in_sizes, int n_in,
                              void* d_out, int out_size, void* d_ws, size_t ws_size,
                              hipStream_t stream) {
  const float* hs  = (const float*)d_in[0];
  const int*   tok = (const int*)d_in[1];
  const float* mu  = (const float*)d_in[2];
  const float* wg  = (const float*)d_in[3];
  const float* wu  = (const float*)d_in[4];
  const float* wd  = (const float*)d_in[5];
  const float* mrw = (const float*)d_in[6];
  float* out = (float*)d_out;
  char* ws = (char*)d_ws;

  unsigned short* Xs  = (unsigned short*)(ws + WS_XS);
  unsigned short* WgT = (unsigned short*)(ws + WS_WGT);
  unsigned short* WuT = (unsigned short*)(ws + WS_WUT);
  unsigned short* WdT = (unsigned short*)(ws + WS_WDT);
  unsigned short* Hb  = (unsigned short*)(ws + WS_HB);
  int* eid      = (int*)(ws + WS_EID);
  int* tokofrow = (int*)(ws + WS_TOK);
  int* offsets   = (int*)(ws + WS_OFF);  // [9]
  int* tileOff   = offsets + 16;         // [9]  256-gran (gemm1)
  int* tileOff128= offsets + 32;         // [9]  128-gran (gemm2)
  int* blockCnt = (int*)(ws + WS_BC);    // [1024][8]
  int* blockBase= (int*)(ws + WS_BB);    // [1024][8]

  k_pre<<<4096, 256, 0, stream>>>(mu, tok, mrw, eid, blockCnt,
                                  wg, wu, wd, WgT, WuT, WdT);
  k_scan2<<<1, 1024, 0, stream>>>(blockCnt, blockBase, offsets, tileOff, tileOff128);
  k_gather<<<1024, 256, 0, stream>>>(hs, eid, blockBase, tokofrow, Xs);
  // gemm1: worst-case M-tiles(256) = 71; x4 n-tiles = 284
  k_gemm1<<<284, 512, 0, stream>>>(Xs, WgT, WuT, Hb, offsets, tileOff);
  // gemm2: worst-case M-tiles(128) = 135; x8 n-tiles = 1080
  k_gemm2<<<135 * 8, 512, 0, stream>>>(Hb, WdT, out, offsets, tileOff128, tokofrow);
}

// Round 14
// 154.642 us; speedup vs baseline: 1.7850x; 1.0798x over previous
//
#include <hip/hip_runtime.h>
#include <stdint.h>

// Problem constants
#define T_TOK   16384      // B*S
#define H_DIM   1024
#define IE_DIM  512
#define E_NUM   8
#define V_MAX   100000

typedef __attribute__((ext_vector_type(8))) short bf16x8;
typedef __attribute__((ext_vector_type(4))) float f32x4;
typedef unsigned long long ull;

__device__ __forceinline__ unsigned short f2bf(float f) {
  union { float f; unsigned u; } v; v.f = f;
  unsigned r = v.u + 0x7fffu + ((v.u >> 16) & 1u);
  return (unsigned short)(r >> 16);
}

__device__ __forceinline__ void gload16(const void* g, void* l) {
  __builtin_amdgcn_global_load_lds(
      (const __attribute__((address_space(1))) unsigned int*)g,
      (__attribute__((address_space(3))) unsigned int*)(unsigned int)(uintptr_t)l,
      16, 0, 0);
}

// ---------------- route: 16 tokens/block, eid + per-block histogram ----------------
__global__ __launch_bounds__(256) void k_route(
    const float* __restrict__ mu, const int* __restrict__ tok,
    const float* __restrict__ mrw, int* __restrict__ eid,
    int* __restrict__ blockCnt) {
  __shared__ int cnt[8];
  int tid = threadIdx.x;
  if (tid < 8) cnt[tid] = 0;
  int wv = blockIdx.x * 4 + (tid >> 6);
  int t0 = wv * 4;
  int lane = tid & 63;
  const float4* mrw4 = (const float4*)mrw;

  float acc[4][E_NUM];
#pragma unroll
  for (int i = 0; i < 4; i++)
#pragma unroll
    for (int e = 0; e < E_NUM; e++) acc[i][e] = 0.f;

#pragma unroll
  for (int j = 0; j < 4; j++) {
    int idx = lane + 64 * j;
    float4 wr[E_NUM];
#pragma unroll
    for (int e = 0; e < E_NUM; e++) wr[e] = mrw4[e * 256 + idx];
#pragma unroll
    for (int i = 0; i < 4; i++) {
      float4 m = ((const float4*)(mu + (size_t)(t0 + i) * H_DIM))[idx];
#pragma unroll
      for (int e = 0; e < E_NUM; e++)
        acc[i][e] += m.x * wr[e].x + m.y * wr[e].y + m.z * wr[e].z + m.w * wr[e].w;
    }
  }
#pragma unroll
  for (int i = 0; i < 4; i++)
#pragma unroll
    for (int e = 0; e < E_NUM; e++)
#pragma unroll
      for (int off = 32; off >= 1; off >>= 1)
        acc[i][e] += __shfl_xor(acc[i][e], off, 64);

  __syncthreads();
#pragma unroll
  for (int i = 0; i < 4; i++) {
    int tv = tok[t0 + i];
    if (tv < 0) tv = 0;
    if (tv > V_MAX - 1) tv = V_MAX - 1;
    int base = tv & 7;
    int best = 0; float bs = -1e30f;
#pragma unroll
    for (int e = 0; e < E_NUM; e++) {
      float s = acc[i][e] + (e == base ? 10.f : 0.f);
      if (s > bs) { bs = s; best = e; }
    }
    if (lane == i) {
      eid[t0 + i] = best;
      atomicAdd(&cnt[best], 1);
    }
  }
  __syncthreads();
  if (tid < 8) blockCnt[blockIdx.x * 8 + tid] = cnt[tid];
}

// ---------------- scan: packed 8x16-bit Hillis-Steele over 1024 blocks ----------------
__global__ __launch_bounds__(1024) void k_scan2(
    const int* __restrict__ blockCnt, int* __restrict__ blockBase,
    int* __restrict__ offsets, int* __restrict__ tileOff) {
  int b = threadIdx.x;
  __shared__ ull s0[1024], s1[1024];
  __shared__ int offL[8];
  const int4* p = (const int4*)(blockCnt + b * 8);
  int4 x0 = p[0], x1 = p[1];
  int c[8] = {x0.x, x0.y, x0.z, x0.w, x1.x, x1.y, x1.z, x1.w};
  ull v0 = (ull)c[0] | ((ull)c[1] << 16) | ((ull)c[2] << 32) | ((ull)c[3] << 48);
  ull v1 = (ull)c[4] | ((ull)c[5] << 16) | ((ull)c[6] << 32) | ((ull)c[7] << 48);
  s0[b] = v0; s1[b] = v1;
  __syncthreads();
  for (int st = 1; st < 1024; st <<= 1) {
    ull a0 = 0, a1 = 0;
    if (b >= st) { a0 = s0[b - st]; a1 = s1[b - st]; }
    __syncthreads();
    v0 += a0; v1 += a1;
    s0[b] = v0; s1[b] = v1;
    __syncthreads();
  }
  if (b == 1023) {
    int tot[8];
#pragma unroll
    for (int e = 0; e < 4; e++) tot[e] = (int)((v0 >> (16 * e)) & 0xFFFF);
#pragma unroll
    for (int e = 0; e < 4; e++) tot[4 + e] = (int)((v1 >> (16 * e)) & 0xFFFF);
    int s = 0, ts = 0;
    for (int e = 0; e < E_NUM; e++) {
      offsets[e] = s; offL[e] = s; tileOff[e] = ts;
      s += tot[e];
      ts += (tot[e] + 127) >> 7;     // 128-row M-tiles
    }
    offsets[E_NUM] = s; tileOff[E_NUM] = ts;
  }
  __syncthreads();
  int be[8];
#pragma unroll
  for (int e = 0; e < 4; e++)
    be[e] = offL[e] + (int)((v0 >> (16 * e)) & 0xFFFF) - c[e];
#pragma unroll
  for (int e = 0; e < 4; e++)
    be[4 + e] = offL[4 + e] + (int)((v1 >> (16 * e)) & 0xFFFF) - c[4 + e];
  int4* q = (int4*)(blockBase + b * 8);
  q[0] = make_int4(be[0], be[1], be[2], be[3]);
  q[1] = make_int4(be[4], be[5], be[6], be[7]);
}

// ---------------- fused gather (blocks 0..1023) + weight transpose (1024..4095) ----------------
__global__ __launch_bounds__(256) void k_gathtr(
    const float* __restrict__ hs, const int* __restrict__ eid,
    const int* __restrict__ blockBase, int* __restrict__ tokofrow,
    unsigned short* __restrict__ Xs,
    const float* __restrict__ wg, const float* __restrict__ wu,
    const float* __restrict__ wd, unsigned short* __restrict__ WgT,
    unsigned short* __restrict__ WuT, unsigned short* __restrict__ WdT) {
  __shared__ unsigned short lds[64][72];
  int tid = threadIdx.x;

  if (blockIdx.x < 1024) {
    // ---- gather: deterministic rank, no atomics ----
    int b = blockIdx.x;
    int* eL = (int*)&lds[0][0];
    int* posL = eL + 16;
    if (tid < 16) eL[tid] = eid[b * 16 + tid];
    __syncthreads();
    if (tid < 16) {
      int e = eL[tid];
      int r = 0;
      for (int j = 0; j < tid; j++) r += (eL[j] == e);
      int pos = blockBase[b * 8 + e] + r;
      posL[tid] = pos;
      tokofrow[pos] = b * 16 + tid;
    }
    __syncthreads();
    int w = tid >> 6, lane = tid & 63;
#pragma unroll
    for (int i = 0; i < 4; i++) {
      int li = w * 4 + i;
      int t = b * 16 + li;
      int pos = posL[li];
      const float4* src = (const float4*)(hs + (size_t)t * H_DIM);
      unsigned short* drow = Xs + (size_t)pos * H_DIM;
#pragma unroll
      for (int j = 0; j < 4; j++) {
        float4 v = src[lane + 64 * j];
        ushort4 bb;
        bb.x = f2bf(v.x); bb.y = f2bf(v.y); bb.z = f2bf(v.z); bb.w = f2bf(v.w);
        *(ushort4*)(drow + (lane + 64 * j) * 4) = bb;
      }
    }
  } else {
    // ---- transpose-convert fp32 [R][C] -> bf16 [C][R] ----
    int sel = (blockIdx.x - 1024) >> 10;
    int blk = blockIdx.x & 1023;
    const float* src; unsigned short* dst; int R, C;
    if (sel == 0)      { src = wg; dst = WgT; R = H_DIM; C = IE_DIM; }
    else if (sel == 1) { src = wu; dst = WuT; R = H_DIM; C = IE_DIM; }
    else               { src = wd; dst = WdT; R = IE_DIM; C = H_DIM; }
    int tpe = (R >> 6) * (C >> 6);
    int e = blk / tpe;
    int rem = blk % tpe;
    int tr = rem / (C >> 6);
    int tc = rem % (C >> 6);
    const float* s = src + (size_t)e * R * C;
    unsigned short* d = dst + (size_t)e * R * C;
    int r0 = tid >> 4;
    int c0 = (tid & 15) * 4;
#pragma unroll
    for (int i = 0; i < 4; i++) {
      int r = r0 + i * 16;
      float4 v = *(const float4*)(s + (size_t)(tr * 64 + r) * C + tc * 64 + c0);
      lds[r][c0 + 0] = f2bf(v.x); lds[r][c0 + 1] = f2bf(v.y);
      lds[r][c0 + 2] = f2bf(v.z); lds[r][c0 + 3] = f2bf(v.w);
    }
    __syncthreads();
    int oc = tid >> 2;
    int ob = (tid & 3) * 16;
    unsigned short tmp[16];
#pragma unroll
    for (int i = 0; i < 16; i++) tmp[i] = lds[ob + i][oc];
    uint4* dp = (uint4*)(d + (size_t)(tc * 64 + oc) * R + tr * 64 + ob);
    dp[0] = ((uint4*)tmp)[0];
    dp[1] = ((uint4*)tmp)[1];
  }
}

// ---------------- GEMM1 (R7 proven): h = silu(X Wg) * (X Wu), bf16 out ----------------
// BM=128, BN=128, BK=32. 8 waves (2x4), wave tile 64x32 dual-acc.
// 3-buffer LDS, prefetch depth 2, counted vmcnt(3). XCD swizzle + setprio.
__global__ __launch_bounds__(512) void k_gemm1(
    const unsigned short* __restrict__ Xs,
    const unsigned short* __restrict__ WgT,
    const unsigned short* __restrict__ WuT,
    unsigned short* __restrict__ Hb,
    const int* __restrict__ offsets, const int* __restrict__ tileOff) {
  // bijective XCD swizzle for nwg=540: q=67, r=4
  int bid0 = blockIdx.x;
  int xcd = bid0 & 7, seq = bid0 >> 3;
  int wg = (xcd < 4 ? xcd * 68 : 272 + (xcd - 4) * 67) + seq;
  int nt = wg & 3;
  int mlin = wg >> 2;
  if (mlin >= tileOff[E_NUM]) return;
  int e = 0;
#pragma unroll
  for (int i = 1; i < E_NUM; i++)
    if (mlin >= tileOff[i]) e = i;
  int mtile = mlin - tileOff[e];
  int segStart = offsets[e], segEnd = offsets[e + 1];
  int M = segEnd - segStart;

  __shared__ unsigned short Alds[3][128 * 32];
  __shared__ unsigned short Bglds[3][128 * 32];
  __shared__ unsigned short Bulds[3][128 * 32];

  int tid = threadIdx.x;
  int lane = tid & 63;
  int w = tid >> 6;
  int wm = w >> 2;   // 0..1
  int wn = w & 3;    // 0..3

  f32x4 accg[4][2], accu[4][2];
#pragma unroll
  for (int i = 0; i < 4; i++)
#pragma unroll
    for (int j = 0; j < 2; j++) {
      accg[i][j] = (f32x4)(0.f);
      accu[i][j] = (f32x4)(0.f);
    }

  int sr = tid >> 2;            // 0..127
  int sc = tid & 3;
  int scc = sc ^ ((sr >> 1) & 3);   // involution, mirrored on read
  int grow = mtile * 128 + sr;
  if (grow > M - 1) grow = M - 1;
  const unsigned short* Arow = Xs + (size_t)(segStart + grow) * H_DIM + scc * 8;
  const unsigned short* Bgrow =
      WgT + (size_t)e * IE_DIM * H_DIM + (size_t)(nt * 128 + sr) * H_DIM + scc * 8;
  const unsigned short* Burow =
      WuT + (size_t)e * IE_DIM * H_DIM + (size_t)(nt * 128 + sr) * H_DIM + scc * 8;

#define STAGE1(buf, k0)                                            \
  {                                                                \
    gload16(Arow + (k0), (char*)Alds[buf] + tid * 16);             \
    gload16(Bgrow + (k0), (char*)Bglds[buf] + tid * 16);           \
    gload16(Burow + (k0), (char*)Bulds[buf] + tid * 16);           \
  }

  int kc = lane >> 4;           // 0..3
  int arow[4], browv[2];
#pragma unroll
  for (int mf = 0; mf < 4; mf++) arow[mf] = wm * 64 + mf * 16 + (lane & 15);
#pragma unroll
  for (int nf = 0; nf < 2; nf++) browv[nf] = wn * 32 + nf * 16 + (lane & 15);

  const int NT = H_DIM / 32;    // 32
  STAGE1(0, 0);
  STAGE1(1, 32);                // 6 loads in flight

  int cur = 0;
  for (int t = 0; t < NT; t++) {
    asm volatile("s_waitcnt vmcnt(3)" ::: "memory");
    __builtin_amdgcn_s_barrier();
    __builtin_amdgcn_sched_barrier(0);
    int tn = t + 2; if (tn >= NT) tn -= NT;
    int nbuf = cur + 2; if (nbuf >= 3) nbuf -= 3;
    STAGE1(nbuf, tn * 32);

    bf16x8 a[4], bg[2], bu[2];
#pragma unroll
    for (int mf = 0; mf < 4; mf++) {
      int row = arow[mf];
      int byte = row * 64 + ((kc ^ ((row >> 1) & 3)) << 4);
      a[mf] = *(const bf16x8*)((const char*)Alds[cur] + byte);
    }
#pragma unroll
    for (int nf = 0; nf < 2; nf++) {
      int row = browv[nf];
      int byte = row * 64 + ((kc ^ ((row >> 1) & 3)) << 4);
      bg[nf] = *(const bf16x8*)((const char*)Bglds[cur] + byte);
      bu[nf] = *(const bf16x8*)((const char*)Bulds[cur] + byte);
    }
    __builtin_amdgcn_s_setprio(1);
#pragma unroll
    for (int mf = 0; mf < 4; mf++)
#pragma unroll
      for (int nf = 0; nf < 2; nf++) {
        accg[mf][nf] = __builtin_amdgcn_mfma_f32_16x16x32_bf16(
            a[mf], bg[nf], accg[mf][nf], 0, 0, 0);
        accu[mf][nf] = __builtin_amdgcn_mfma_f32_16x16x32_bf16(
            a[mf], bu[nf], accu[mf][nf], 0, 0, 0);
      }
    __builtin_amdgcn_s_setprio(0);
    cur = (cur + 1 == 3) ? 0 : cur + 1;
  }
#undef STAGE1
  asm volatile("s_waitcnt vmcnt(0)" ::: "memory");

  int rowBase = segStart + mtile * 128 + wm * 64;
#pragma unroll
  for (int mf = 0; mf < 4; mf++)
#pragma unroll
    for (int nf = 0; nf < 2; nf++) {
      int col = nt * 128 + wn * 32 + nf * 16 + (lane & 15);
#pragma unroll
      for (int j = 0; j < 4; j++) {
        int r = rowBase + mf * 16 + (lane >> 4) * 4 + j;
        if (r < segEnd) {
          float g = accg[mf][nf][j];
          float u = accu[mf][nf][j];
          float h = (g / (1.f + __expf(-g))) * u;
          Hb[(size_t)r * IE_DIM + col] = f2bf(h);
        }
      }
    }
}

// ---------------- GEMM2 (R7 proven): out[tok] = h Wd, fp32 scatter ----------------
__global__ __launch_bounds__(512) void k_gemm2(
    const unsigned short* __restrict__ Hb,
    const unsigned short* __restrict__ WdT,
    float* __restrict__ out,
    const int* __restrict__ offsets, const int* __restrict__ tileOff,
    const int* __restrict__ tokofrow) {
  // bijective XCD swizzle for nwg=1080: q=135, r=0
  int bid0 = blockIdx.x;
  int wg = (bid0 & 7) * 135 + (bid0 >> 3);
  int nt = wg & 7;
  int mlin = wg >> 3;
  if (mlin >= tileOff[E_NUM]) return;
  int e = 0;
#pragma unroll
  for (int i = 1; i < E_NUM; i++)
    if (mlin >= tileOff[i]) e = i;
  int mtile = mlin - tileOff[e];
  int segStart = offsets[e], segEnd = offsets[e + 1];
  int M = segEnd - segStart;

  __shared__ unsigned short Alds[3][128 * 32];
  __shared__ unsigned short Blds[3][128 * 32];

  int tid = threadIdx.x;
  int lane = tid & 63;
  int w = tid >> 6;
  int wm = w >> 2;
  int wn = w & 3;

  f32x4 acc[4][2];
#pragma unroll
  for (int i = 0; i < 4; i++)
#pragma unroll
    for (int j = 0; j < 2; j++) acc[i][j] = (f32x4)(0.f);

  int sr = tid >> 2;
  int sc = tid & 3;
  int scc = sc ^ ((sr >> 1) & 3);
  int grow = mtile * 128 + sr;
  if (grow > M - 1) grow = M - 1;
  const unsigned short* Arow = Hb + (size_t)(segStart + grow) * IE_DIM + scc * 8;
  const unsigned short* Brow =
      WdT + (size_t)e * H_DIM * IE_DIM + (size_t)(nt * 128 + sr) * IE_DIM + scc * 8;

#define STAGE2(buf, k0)                                            \
  {                                                                \
    gload16(Arow + (k0), (char*)Alds[buf] + tid * 16);             \
    gload16(Brow + (k0), (char*)Blds[buf] + tid * 16);             \
  }

  int kc = lane >> 4;
  int arow[4], browv[2];
#pragma unroll
  for (int mf = 0; mf < 4; mf++) arow[mf] = wm * 64 + mf * 16 + (lane & 15);
#pragma unroll
  for (int nf = 0; nf < 2; nf++) browv[nf] = wn * 32 + nf * 16 + (lane & 15);

  const int NT = IE_DIM / 32;
  STAGE2(0, 0);
  STAGE2(1, 32);

  int cur = 0;
  for (int t = 0; t < NT; t++) {
    asm volatile("s_waitcnt vmcnt(2)" ::: "memory");
    __builtin_amdgcn_s_barrier();
    __builtin_amdgcn_sched_barrier(0);
    int tn = t + 2; if (tn >= NT) tn -= NT;
    int nbuf = cur + 2; if (nbuf >= 3) nbuf -= 3;
    STAGE2(nbuf, tn * 32);

    bf16x8 a[4], b[2];
#pragma unroll
    for (int mf = 0; mf < 4; mf++) {
      int row = arow[mf];
      int byte = row * 64 + ((kc ^ ((row >> 1) & 3)) << 4);
      a[mf] = *(const bf16x8*)((const char*)Alds[cur] + byte);
    }
#pragma unroll
    for (int nf = 0; nf < 2; nf++) {
      int row = browv[nf];
      int byte = row * 64 + ((kc ^ ((row >> 1) & 3)) << 4);
      b[nf] = *(const bf16x8*)((const char*)Blds[cur] + byte);
    }
    __builtin_amdgcn_s_setprio(1);
#pragma unroll
    for (int mf = 0; mf < 4; mf++)
#pragma unroll
      for (int nf = 0; nf < 2; nf++)
        acc[mf][nf] = __builtin_amdgcn_mfma_f32_16x16x32_bf16(
            a[mf], b[nf], acc[mf][nf], 0, 0, 0);
    __builtin_amdgcn_s_setprio(0);
    cur = (cur + 1 == 3) ? 0 : cur + 1;
  }
#undef STAGE2
  asm volatile("s_waitcnt vmcnt(0)" ::: "memory");

  int rowBase = segStart + mtile * 128 + wm * 64;
#pragma unroll
  for (int mf = 0; mf < 4; mf++)
#pragma unroll
    for (int nf = 0; nf < 2; nf++) {
      int col = nt * 128 + wn * 32 + nf * 16 + (lane & 15);
#pragma unroll
      for (int j = 0; j < 4; j++) {
        int r = rowBase + mf * 16 + (lane >> 4) * 4 + j;
        if (r < segEnd) {
          int t = tokofrow[r];
          out[(size_t)t * H_DIM + col] = acc[mf][nf][j];
        }
      }
    }
}

// ---------------- workspace layout (bytes) ----------------
#define WS_XS    ((size_t)0)             // 32MB
#define WS_WGT   ((size_t)33554432)      // 8MB
#define WS_WUT   ((size_t)41943040)      // 8MB
#define WS_WDT   ((size_t)50331648)      // 8MB
#define WS_HB    ((size_t)58720256)      // 16MB
#define WS_EID   ((size_t)75497472)      // 64KB
#define WS_TOK   ((size_t)75563008)      // 64KB
#define WS_OFF   ((size_t)75628544)      // offsets/tileOff (1KB)
#define WS_BC    ((size_t)75629568)      // blockCnt 32KB
#define WS_BB    ((size_t)75662336)      // blockBase 32KB

extern "C" void kernel_launch(void* const* d_in, const int* in_sizes, int n_in,
                              void* d_out, int out_size, void* d_ws, size_t ws_size,
                              hipStream_t stream) {
  const float* hs  = (const float*)d_in[0];
  const int*   tok = (const int*)d_in[1];
  const float* mu  = (const float*)d_in[2];
  const float* wg  = (const float*)d_in[3];
  const float* wu  = (const float*)d_in[4];
  const float* wd  = (const float*)d_in[5];
  const float* mrw = (const float*)d_in[6];
  float* out = (float*)d_out;
  char* ws = (char*)d_ws;

  unsigned short* Xs  = (unsigned short*)(ws + WS_XS);
  unsigned short* WgT = (unsigned short*)(ws + WS_WGT);
  unsigned short* WuT = (unsigned short*)(ws + WS_WUT);
  unsigned short* WdT = (unsigned short*)(ws + WS_WDT);
  unsigned short* Hb  = (unsigned short*)(ws + WS_HB);
  int* eid      = (int*)(ws + WS_EID);
  int* tokofrow = (int*)(ws + WS_TOK);
  int* offsets  = (int*)(ws + WS_OFF);   // [9]
  int* tileOff  = offsets + 16;          // [9]  128-gran
  int* blockCnt = (int*)(ws + WS_BC);    // [1024][8]
  int* blockBase= (int*)(ws + WS_BB);    // [1024][8]

  k_route<<<1024, 256, 0, stream>>>(mu, tok, mrw, eid, blockCnt);
  k_scan2<<<1, 1024, 0, stream>>>(blockCnt, blockBase, offsets, tileOff);
  k_gathtr<<<4096, 256, 0, stream>>>(hs, eid, blockBase, tokofrow, Xs,
                                     wg, wu, wd, WgT, WuT, WdT);
  // gemm1: worst-case M-tiles(128) = 135; x4 n-tiles = 540
  k_gemm1<<<135 * 4, 512, 0, stream>>>(Xs, WgT, WuT, Hb, offsets, tileOff);
  // gemm2: 135 x8 n-tiles = 1080
  k_gemm2<<<135 * 8, 512, 0, stream>>>(Hb, WdT, out, offsets, tileOff, tokofrow);
}

// Round 16
// 154.405 us; speedup vs baseline: 1.7877x; 1.0015x over previous
//
#include <hip/hip_runtime.h>
#include <stdint.h>

// Problem constants
#define T_TOK   16384      // B*S
#define H_DIM   1024
#define IE_DIM  512
#define E_NUM   8
#define V_MAX   100000

typedef __attribute__((ext_vector_type(8))) short bf16x8;
typedef __attribute__((ext_vector_type(4))) float f32x4;
typedef unsigned long long ull;

__device__ __forceinline__ unsigned short f2bf(float f) {
  union { float f; unsigned u; } v; v.f = f;
  unsigned r = v.u + 0x7fffu + ((v.u >> 16) & 1u);
  return (unsigned short)(r >> 16);
}

__device__ __forceinline__ void gload16(const void* g, void* l) {
  __builtin_amdgcn_global_load_lds(
      (const __attribute__((address_space(1))) unsigned int*)g,
      (__attribute__((address_space(3))) unsigned int*)(unsigned int)(uintptr_t)l,
      16, 0, 0);
}

// ---------------- route: 16 tokens/block, eid + per-block histogram ----------------
__global__ __launch_bounds__(256) void k_route(
    const float* __restrict__ mu, const int* __restrict__ tok,
    const float* __restrict__ mrw, int* __restrict__ eid,
    int* __restrict__ blockCnt) {
  __shared__ int cnt[8];
  int tid = threadIdx.x;
  if (tid < 8) cnt[tid] = 0;
  int wv = blockIdx.x * 4 + (tid >> 6);
  int t0 = wv * 4;
  int lane = tid & 63;
  const float4* mrw4 = (const float4*)mrw;

  float acc[4][E_NUM];
#pragma unroll
  for (int i = 0; i < 4; i++)
#pragma unroll
    for (int e = 0; e < E_NUM; e++) acc[i][e] = 0.f;

#pragma unroll
  for (int j = 0; j < 4; j++) {
    int idx = lane + 64 * j;
    float4 wr[E_NUM];
#pragma unroll
    for (int e = 0; e < E_NUM; e++) wr[e] = mrw4[e * 256 + idx];
#pragma unroll
    for (int i = 0; i < 4; i++) {
      float4 m = ((const float4*)(mu + (size_t)(t0 + i) * H_DIM))[idx];
#pragma unroll
      for (int e = 0; e < E_NUM; e++)
        acc[i][e] += m.x * wr[e].x + m.y * wr[e].y + m.z * wr[e].z + m.w * wr[e].w;
    }
  }
#pragma unroll
  for (int i = 0; i < 4; i++)
#pragma unroll
    for (int e = 0; e < E_NUM; e++)
#pragma unroll
      for (int off = 32; off >= 1; off >>= 1)
        acc[i][e] += __shfl_xor(acc[i][e], off, 64);

  __syncthreads();
#pragma unroll
  for (int i = 0; i < 4; i++) {
    int tv = tok[t0 + i];
    if (tv < 0) tv = 0;
    if (tv > V_MAX - 1) tv = V_MAX - 1;
    int base = tv & 7;
    int best = 0; float bs = -1e30f;
#pragma unroll
    for (int e = 0; e < E_NUM; e++) {
      float s = acc[i][e] + (e == base ? 10.f : 0.f);
      if (s > bs) { bs = s; best = e; }
    }
    if (lane == i) {
      eid[t0 + i] = best;
      atomicAdd(&cnt[best], 1);
    }
  }
  __syncthreads();
  if (tid < 8) blockCnt[blockIdx.x * 8 + tid] = cnt[tid];
}

// ---------------- scan: packed 8x16-bit Hillis-Steele over 1024 blocks ----------------
__global__ __launch_bounds__(1024) void k_scan2(
    const int* __restrict__ blockCnt, int* __restrict__ blockBase,
    int* __restrict__ offsets, int* __restrict__ tileOff) {
  int b = threadIdx.x;
  __shared__ ull s0[1024], s1[1024];
  __shared__ int offL[8];
  const int4* p = (const int4*)(blockCnt + b * 8);
  int4 x0 = p[0], x1 = p[1];
  int c[8] = {x0.x, x0.y, x0.z, x0.w, x1.x, x1.y, x1.z, x1.w};
  ull v0 = (ull)c[0] | ((ull)c[1] << 16) | ((ull)c[2] << 32) | ((ull)c[3] << 48);
  ull v1 = (ull)c[4] | ((ull)c[5] << 16) | ((ull)c[6] << 32) | ((ull)c[7] << 48);
  s0[b] = v0; s1[b] = v1;
  __syncthreads();
  for (int st = 1; st < 1024; st <<= 1) {
    ull a0 = 0, a1 = 0;
    if (b >= st) { a0 = s0[b - st]; a1 = s1[b - st]; }
    __syncthreads();
    v0 += a0; v1 += a1;
    s0[b] = v0; s1[b] = v1;
    __syncthreads();
  }
  if (b == 1023) {
    int tot[8];
#pragma unroll
    for (int e = 0; e < 4; e++) tot[e] = (int)((v0 >> (16 * e)) & 0xFFFF);
#pragma unroll
    for (int e = 0; e < 4; e++) tot[4 + e] = (int)((v1 >> (16 * e)) & 0xFFFF);
    int s = 0, ts = 0;
    for (int e = 0; e < E_NUM; e++) {
      offsets[e] = s; offL[e] = s; tileOff[e] = ts;
      s += tot[e];
      ts += (tot[e] + 127) >> 7;     // 128-row M-tiles
    }
    offsets[E_NUM] = s; tileOff[E_NUM] = ts;
  }
  __syncthreads();
  int be[8];
#pragma unroll
  for (int e = 0; e < 4; e++)
    be[e] = offL[e] + (int)((v0 >> (16 * e)) & 0xFFFF) - c[e];
#pragma unroll
  for (int e = 0; e < 4; e++)
    be[4 + e] = offL[4 + e] + (int)((v1 >> (16 * e)) & 0xFFFF) - c[4 + e];
  int4* q = (int4*)(blockBase + b * 8);
  q[0] = make_int4(be[0], be[1], be[2], be[3]);
  q[1] = make_int4(be[4], be[5], be[6], be[7]);
}

// ---------------- fused gather (blocks 0..1023) + weight transpose (1024..4095) ----------------
__global__ __launch_bounds__(256) void k_gathtr(
    const float* __restrict__ hs, const int* __restrict__ eid,
    const int* __restrict__ blockBase, int* __restrict__ tokofrow,
    unsigned short* __restrict__ Xs,
    const float* __restrict__ wg, const float* __restrict__ wu,
    const float* __restrict__ wd, unsigned short* __restrict__ WgT,
    unsigned short* __restrict__ WuT, unsigned short* __restrict__ WdT) {
  __shared__ unsigned short lds[64][72];
  int tid = threadIdx.x;

  if (blockIdx.x < 1024) {
    // ---- gather: deterministic rank, no atomics ----
    int b = blockIdx.x;
    int* eL = (int*)&lds[0][0];
    int* posL = eL + 16;
    if (tid < 16) eL[tid] = eid[b * 16 + tid];
    __syncthreads();
    if (tid < 16) {
      int e = eL[tid];
      int r = 0;
      for (int j = 0; j < tid; j++) r += (eL[j] == e);
      int pos = blockBase[b * 8 + e] + r;
      posL[tid] = pos;
      tokofrow[pos] = b * 16 + tid;
    }
    __syncthreads();
    int w = tid >> 6, lane = tid & 63;
#pragma unroll
    for (int i = 0; i < 4; i++) {
      int li = w * 4 + i;
      int t = b * 16 + li;
      int pos = posL[li];
      const float4* src = (const float4*)(hs + (size_t)t * H_DIM);
      unsigned short* drow = Xs + (size_t)pos * H_DIM;
#pragma unroll
      for (int j = 0; j < 4; j++) {
        float4 v = src[lane + 64 * j];
        ushort4 bb;
        bb.x = f2bf(v.x); bb.y = f2bf(v.y); bb.z = f2bf(v.z); bb.w = f2bf(v.w);
        *(ushort4*)(drow + (lane + 64 * j) * 4) = bb;
      }
    }
  } else {
    // ---- transpose-convert fp32 [R][C] -> bf16 [C][R] ----
    int sel = (blockIdx.x - 1024) >> 10;
    int blk = blockIdx.x & 1023;
    const float* src; unsigned short* dst; int R, C;
    if (sel == 0)      { src = wg; dst = WgT; R = H_DIM; C = IE_DIM; }
    else if (sel == 1) { src = wu; dst = WuT; R = H_DIM; C = IE_DIM; }
    else               { src = wd; dst = WdT; R = IE_DIM; C = H_DIM; }
    int tpe = (R >> 6) * (C >> 6);
    int e = blk / tpe;
    int rem = blk % tpe;
    int tr = rem / (C >> 6);
    int tc = rem % (C >> 6);
    const float* s = src + (size_t)e * R * C;
    unsigned short* d = dst + (size_t)e * R * C;
    int r0 = tid >> 4;
    int c0 = (tid & 15) * 4;
#pragma unroll
    for (int i = 0; i < 4; i++) {
      int r = r0 + i * 16;
      float4 v = *(const float4*)(s + (size_t)(tr * 64 + r) * C + tc * 64 + c0);
      lds[r][c0 + 0] = f2bf(v.x); lds[r][c0 + 1] = f2bf(v.y);
      lds[r][c0 + 2] = f2bf(v.z); lds[r][c0 + 3] = f2bf(v.w);
    }
    __syncthreads();
    int oc = tid >> 2;
    int ob = (tid & 3) * 16;
    unsigned short tmp[16];
#pragma unroll
    for (int i = 0; i < 16; i++) tmp[i] = lds[ob + i][oc];
    uint4* dp = (uint4*)(d + (size_t)(tc * 64 + oc) * R + tr * 64 + ob);
    dp[0] = ((uint4*)tmp)[0];
    dp[1] = ((uint4*)tmp)[1];
  }
}

// ---------------- GEMM1 (R7 proven): h = silu(X Wg) * (X Wu), bf16 out ----------------
// BM=128, BN=128, BK=32. 8 waves (2x4), wave tile 64x32 dual-acc.
// 3-buffer LDS, prefetch depth 2, counted vmcnt(3). XCD swizzle + setprio.
__global__ __launch_bounds__(512) void k_gemm1(
    const unsigned short* __restrict__ Xs,
    const unsigned short* __restrict__ WgT,
    const unsigned short* __restrict__ WuT,
    unsigned short* __restrict__ Hb,
    const int* __restrict__ offsets, const int* __restrict__ tileOff) {
  // bijective XCD swizzle for nwg=540: q=67, r=4
  int bid0 = blockIdx.x;
  int xcd = bid0 & 7, seq = bid0 >> 3;
  int wg = (xcd < 4 ? xcd * 68 : 272 + (xcd - 4) * 67) + seq;
  int nt = wg & 3;
  int mlin = wg >> 2;
  if (mlin >= tileOff[E_NUM]) return;
  int e = 0;
#pragma unroll
  for (int i = 1; i < E_NUM; i++)
    if (mlin >= tileOff[i]) e = i;
  int mtile = mlin - tileOff[e];
  int segStart = offsets[e], segEnd = offsets[e + 1];
  int M = segEnd - segStart;

  __shared__ unsigned short Alds[3][128 * 32];
  __shared__ unsigned short Bglds[3][128 * 32];
  __shared__ unsigned short Bulds[3][128 * 32];

  int tid = threadIdx.x;
  int lane = tid & 63;
  int w = tid >> 6;
  int wm = w >> 2;   // 0..1
  int wn = w & 3;    // 0..3

  f32x4 accg[4][2], accu[4][2];
#pragma unroll
  for (int i = 0; i < 4; i++)
#pragma unroll
    for (int j = 0; j < 2; j++) {
      accg[i][j] = (f32x4)(0.f);
      accu[i][j] = (f32x4)(0.f);
    }

  int sr = tid >> 2;            // 0..127
  int sc = tid & 3;
  int scc = sc ^ ((sr >> 1) & 3);   // involution, mirrored on read
  int grow = mtile * 128 + sr;
  if (grow > M - 1) grow = M - 1;
  const unsigned short* Arow = Xs + (size_t)(segStart + grow) * H_DIM + scc * 8;
  const unsigned short* Bgrow =
      WgT + (size_t)e * IE_DIM * H_DIM + (size_t)(nt * 128 + sr) * H_DIM + scc * 8;
  const unsigned short* Burow =
      WuT + (size_t)e * IE_DIM * H_DIM + (size_t)(nt * 128 + sr) * H_DIM + scc * 8;

#define STAGE1(buf, k0)                                            \
  {                                                                \
    gload16(Arow + (k0), (char*)Alds[buf] + tid * 16);             \
    gload16(Bgrow + (k0), (char*)Bglds[buf] + tid * 16);           \
    gload16(Burow + (k0), (char*)Bulds[buf] + tid * 16);           \
  }

  int kc = lane >> 4;           // 0..3
  int arow[4], browv[2];
#pragma unroll
  for (int mf = 0; mf < 4; mf++) arow[mf] = wm * 64 + mf * 16 + (lane & 15);
#pragma unroll
  for (int nf = 0; nf < 2; nf++) browv[nf] = wn * 32 + nf * 16 + (lane & 15);

  const int NT = H_DIM / 32;    // 32
  STAGE1(0, 0);
  STAGE1(1, 32);                // 6 loads in flight

  int cur = 0;
  for (int t = 0; t < NT; t++) {
    asm volatile("s_waitcnt vmcnt(3)" ::: "memory");
    __builtin_amdgcn_s_barrier();
    __builtin_amdgcn_sched_barrier(0);
    int tn = t + 2; if (tn >= NT) tn -= NT;
    int nbuf = cur + 2; if (nbuf >= 3) nbuf -= 3;
    STAGE1(nbuf, tn * 32);

    bf16x8 a[4], bg[2], bu[2];
#pragma unroll
    for (int mf = 0; mf < 4; mf++) {
      int row = arow[mf];
      int byte = row * 64 + ((kc ^ ((row >> 1) & 3)) << 4);
      a[mf] = *(const bf16x8*)((const char*)Alds[cur] + byte);
    }
#pragma unroll
    for (int nf = 0; nf < 2; nf++) {
      int row = browv[nf];
      int byte = row * 64 + ((kc ^ ((row >> 1) & 3)) << 4);
      bg[nf] = *(const bf16x8*)((const char*)Bglds[cur] + byte);
      bu[nf] = *(const bf16x8*)((const char*)Bulds[cur] + byte);
    }
    __builtin_amdgcn_s_setprio(1);
#pragma unroll
    for (int mf = 0; mf < 4; mf++)
#pragma unroll
      for (int nf = 0; nf < 2; nf++) {
        accg[mf][nf] = __builtin_amdgcn_mfma_f32_16x16x32_bf16(
            a[mf], bg[nf], accg[mf][nf], 0, 0, 0);
        accu[mf][nf] = __builtin_amdgcn_mfma_f32_16x16x32_bf16(
            a[mf], bu[nf], accu[mf][nf], 0, 0, 0);
      }
    __builtin_amdgcn_s_setprio(0);
    cur = (cur + 1 == 3) ? 0 : cur + 1;
  }
#undef STAGE1
  asm volatile("s_waitcnt vmcnt(0)" ::: "memory");

  int rowBase = segStart + mtile * 128 + wm * 64;
#pragma unroll
  for (int mf = 0; mf < 4; mf++)
#pragma unroll
    for (int nf = 0; nf < 2; nf++) {
      int col = nt * 128 + wn * 32 + nf * 16 + (lane & 15);
#pragma unroll
      for (int j = 0; j < 4; j++) {
        int r = rowBase + mf * 16 + (lane >> 4) * 4 + j;
        if (r < segEnd) {
          float g = accg[mf][nf][j];
          float u = accu[mf][nf][j];
          float h = (g / (1.f + __expf(-g))) * u;
          Hb[(size_t)r * IE_DIM + col] = f2bf(h);
        }
      }
    }
}

// ---------------- GEMM2 (R7 proven): out[tok] = h Wd, fp32 scatter ----------------
__global__ __launch_bounds__(512) void k_gemm2(
    const unsigned short* __restrict__ Hb,
    const unsigned short* __restrict__ WdT,
    float* __restrict__ out,
    const int* __restrict__ offsets, const int* __restrict__ tileOff,
    const int* __restrict__ tokofrow) {
  // bijective XCD swizzle for nwg=1080: q=135, r=0
  int bid0 = blockIdx.x;
  int wg = (bid0 & 7) * 135 + (bid0 >> 3);
  int nt = wg & 7;
  int mlin = wg >> 3;
  if (mlin >= tileOff[E_NUM]) return;
  int e = 0;
#pragma unroll
  for (int i = 1; i < E_NUM; i++)
    if (mlin >= tileOff[i]) e = i;
  int mtile = mlin - tileOff[e];
  int segStart = offsets[e], segEnd = offsets[e + 1];
  int M = segEnd - segStart;

  __shared__ unsigned short Alds[3][128 * 32];
  __shared__ unsigned short Blds[3][128 * 32];

  int tid = threadIdx.x;
  int lane = tid & 63;
  int w = tid >> 6;
  int wm = w >> 2;
  int wn = w & 3;

  f32x4 acc[4][2];
#pragma unroll
  for (int i = 0; i < 4; i++)
#pragma unroll
    for (int j = 0; j < 2; j++) acc[i][j] = (f32x4)(0.f);

  int sr = tid >> 2;
  int sc = tid & 3;
  int scc = sc ^ ((sr >> 1) & 3);
  int grow = mtile * 128 + sr;
  if (grow > M - 1) grow = M - 1;
  const unsigned short* Arow = Hb + (size_t)(segStart + grow) * IE_DIM + scc * 8;
  const unsigned short* Brow =
      WdT + (size_t)e * H_DIM * IE_DIM + (size_t)(nt * 128 + sr) * IE_DIM + scc * 8;

#define STAGE2(buf, k0)                                            \
  {                                                                \
    gload16(Arow + (k0), (char*)Alds[buf] + tid * 16);             \
    gload16(Brow + (k0), (char*)Blds[buf] + tid * 16);             \
  }

  int kc = lane >> 4;
  int arow[4], browv[2];
#pragma unroll
  for (int mf = 0; mf < 4; mf++) arow[mf] = wm * 64 + mf * 16 + (lane & 15);
#pragma unroll
  for (int nf = 0; nf < 2; nf++) browv[nf] = wn * 32 + nf * 16 + (lane & 15);

  const int NT = IE_DIM / 32;
  STAGE2(0, 0);
  STAGE2(1, 32);

  int cur = 0;
  for (int t = 0; t < NT; t++) {
    asm volatile("s_waitcnt vmcnt(2)" ::: "memory");
    __builtin_amdgcn_s_barrier();
    __builtin_amdgcn_sched_barrier(0);
    int tn = t + 2; if (tn >= NT) tn -= NT;
    int nbuf = cur + 2; if (nbuf >= 3) nbuf -= 3;
    STAGE2(nbuf, tn * 32);

    bf16x8 a[4], b[2];
#pragma unroll
    for (int mf = 0; mf < 4; mf++) {
      int row = arow[mf];
      int byte = row * 64 + ((kc ^ ((row >> 1) & 3)) << 4);
      a[mf] = *(const bf16x8*)((const char*)Alds[cur] + byte);
    }
#pragma unroll
    for (int nf = 0; nf < 2; nf++) {
      int row = browv[nf];
      int byte = row * 64 + ((kc ^ ((row >> 1) & 3)) << 4);
      b[nf] = *(const bf16x8*)((const char*)Blds[cur] + byte);
    }
    __builtin_amdgcn_s_setprio(1);
#pragma unroll
    for (int mf = 0; mf < 4; mf++)
#pragma unroll
      for (int nf = 0; nf < 2; nf++)
        acc[mf][nf] = __builtin_amdgcn_mfma_f32_16x16x32_bf16(
            a[mf], b[nf], acc[mf][nf], 0, 0, 0);
    __builtin_amdgcn_s_setprio(0);
    cur = (cur + 1 == 3) ? 0 : cur + 1;
  }
#undef STAGE2
  asm volatile("s_waitcnt vmcnt(0)" ::: "memory");

  int rowBase = segStart + mtile * 128 + wm * 64;
#pragma unroll
  for (int mf = 0; mf < 4; mf++)
#pragma unroll
    for (int nf = 0; nf < 2; nf++) {
      int col = nt * 128 + wn * 32 + nf * 16 + (lane & 15);
#pragma unroll
      for (int j = 0; j < 4; j++) {
        int r = rowBase + mf * 16 + (lane >> 4) * 4 + j;
        if (r < segEnd) {
          int t = tokofrow[r];
          out[(size_t)t * H_DIM + col] = acc[mf][nf][j];
        }
      }
    }
}

// ---------------- workspace layout (bytes) ----------------
#define WS_XS    ((size_t)0)             // 32MB
#define WS_WGT   ((size_t)33554432)      // 8MB
#define WS_WUT   ((size_t)41943040)      // 8MB
#define WS_WDT   ((size_t)50331648)      // 8MB
#define WS_HB    ((size_t)58720256)      // 16MB
#define WS_EID   ((size_t)75497472)      // 64KB
#define WS_TOK   ((size_t)75563008)      // 64KB
#define WS_OFF   ((size_t)75628544)      // offsets/tileOff (1KB)
#define WS_BC    ((size_t)75629568)      // blockCnt 32KB
#define WS_BB    ((size_t)75662336)      // blockBase 32KB

extern "C" void kernel_launch(void* const* d_in, const int* in_sizes, int n_in,
                              void* d_out, int out_size, void* d_ws, size_t ws_size,
                              hipStream_t stream) {
  const float* hs  = (const float*)d_in[0];
  const int*   tok = (const int*)d_in[1];
  const float* mu  = (const float*)d_in[2];
  const float* wg  = (const float*)d_in[3];
  const float* wu  = (const float*)d_in[4];
  const float* wd  = (const float*)d_in[5];
  const float* mrw = (const float*)d_in[6];
  float* out = (float*)d_out;
  char* ws = (char*)d_ws;

  unsigned short* Xs  = (unsigned short*)(ws + WS_XS);
  unsigned short* WgT = (unsigned short*)(ws + WS_WGT);
  unsigned short* WuT = (unsigned short*)(ws + WS_WUT);
  unsigned short* WdT = (unsigned short*)(ws + WS_WDT);
  unsigned short* Hb  = (unsigned short*)(ws + WS_HB);
  int* eid      = (int*)(ws + WS_EID);
  int* tokofrow = (int*)(ws + WS_TOK);
  int* offsets  = (int*)(ws + WS_OFF);   // [9]
  int* tileOff  = offsets + 16;          // [9]  128-gran
  int* blockCnt = (int*)(ws + WS_BC);    // [1024][8]
  int* blockBase= (int*)(ws + WS_BB);    // [1024][8]

  k_route<<<1024, 256, 0, stream>>>(mu, tok, mrw, eid, blockCnt);
  k_scan2<<<1, 1024, 0, stream>>>(blockCnt, blockBase, offsets, tileOff);
  k_gathtr<<<4096, 256, 0, stream>>>(hs, eid, blockBase, tokofrow, Xs,
                                     wg, wu, wd, WgT, WuT, WdT);
  // gemm1: worst-case M-tiles(128) = 135; x4 n-tiles = 540
  k_gemm1<<<135 * 4, 512, 0, stream>>>(Xs, WgT, WuT, Hb, offsets, tileOff);
  // gemm2: 135 x8 n-tiles = 1080
  k_gemm2<<<135 * 8, 512, 0, stream>>>(Hb, WdT, out, offsets, tileOff, tokofrow);
}